// Round 15
// baseline (438.177 us; speedup 1.0000x reference)
//
#include <hip/hip_runtime.h>
#include <math.h>

// ---------------------------------------------------------------------------
// FeatureMatching: conv tower -> top-k keypoints -> softmax corr gather ->
// weighted DLT -> LAPACK-faithful sgesdd(QR path) SVD for H = Vh[:,:,-1].
// All f32. B=2, C=256, H=W=64, HW=4096, K=512.
// R11: best-measured conv config (conv3 = R4 loop, grid 256).
// R12: kernel fusion -- resp+sort+qgather -> fm_sortf (reg-fused bitonic
//      j<=2 passes); build folded into comb. 10 -> 7 launches.
// ---------------------------------------------------------------------------

#define HW4 4096
#define NIMG 4   // imgs 0,1 = rgb batches; 2,3 = ir batches

// ws layout (floats)
#define OFF_X1   0L
#define OFF_X2   (OFF_X1 + 4L*128*4096)
#define OFF_RESP (OFF_X2 + 4L*128*4096)
#define OFF_INVN (OFF_RESP + 4L*4096)
#define OFF_TOPI (OFF_INVN + 4L*4096)      /* 4*512 ints */
#define OFF_WTS  (OFF_TOPI + 4L*512)
#define OFF_A    (OFF_WTS + 2L*512)
#define OFF_QN   OFF_X1
#define OFF_PART (OFF_X1 + 65536L)

#define NSPLIT 16   // j-splits in fm_corr (each covers 256 cols)

__device__ __forceinline__ float silu_f(float y) { return y / (1.f + expf(-y)); }

// ---------------- conv1: 1x1 256->128 + BN + SiLU --------------------------
// 8 oc x 4 px per thread; grid 256.
__global__ __launch_bounds__(256) void fm_conv1(
    const float* __restrict__ rgb, const float* __restrict__ ir,
    const float* __restrict__ w, const float* __restrict__ g,
    const float* __restrict__ bb, const float* __restrict__ mm,
    const float* __restrict__ vv, float* __restrict__ x1) {
  __shared__ float wl[256*8];   // [ic][o]
  int bid = blockIdx.x;
  int pblk = bid & 3, ocg = (bid >> 2) & 15, img = bid >> 6;
  int oc0 = ocg * 8;
  int tid = threadIdx.x;
  const float* src = (img < 2) ? (rgb + (long)img*256*HW4) : (ir + (long)(img-2)*256*HW4);
  for (int i = tid; i < 2048; i += 256) {
    int o = i & 7, ic = i >> 3;
    wl[i] = w[(oc0 + o)*256 + ic];
  }
  __syncthreads();
  int p0 = pblk*1024 + tid*4;
  float acc[8][4];
  #pragma unroll
  for (int o = 0; o < 8; ++o)
    #pragma unroll
    for (int j = 0; j < 4; ++j) acc[o][j] = 0.f;
  #pragma unroll 4
  for (int ic = 0; ic < 256; ++ic) {
    float4 v = *(const float4*)(src + (long)ic*HW4 + p0);
    float4 wa = *(const float4*)&wl[ic*8];
    float4 wb = *(const float4*)&wl[ic*8 + 4];
    acc[0][0] = fmaf(wa.x, v.x, acc[0][0]); acc[0][1] = fmaf(wa.x, v.y, acc[0][1]);
    acc[0][2] = fmaf(wa.x, v.z, acc[0][2]); acc[0][3] = fmaf(wa.x, v.w, acc[0][3]);
    acc[1][0] = fmaf(wa.y, v.x, acc[1][0]); acc[1][1] = fmaf(wa.y, v.y, acc[1][1]);
    acc[1][2] = fmaf(wa.y, v.z, acc[1][2]); acc[1][3] = fmaf(wa.y, v.w, acc[1][3]);
    acc[2][0] = fmaf(wa.z, v.x, acc[2][0]); acc[2][1] = fmaf(wa.z, v.y, acc[2][1]);
    acc[2][2] = fmaf(wa.z, v.z, acc[2][2]); acc[2][3] = fmaf(wa.z, v.w, acc[2][3]);
    acc[3][0] = fmaf(wa.w, v.x, acc[3][0]); acc[3][1] = fmaf(wa.w, v.y, acc[3][1]);
    acc[3][2] = fmaf(wa.w, v.z, acc[3][2]); acc[3][3] = fmaf(wa.w, v.w, acc[3][3]);
    acc[4][0] = fmaf(wb.x, v.x, acc[4][0]); acc[4][1] = fmaf(wb.x, v.y, acc[4][1]);
    acc[4][2] = fmaf(wb.x, v.z, acc[4][2]); acc[4][3] = fmaf(wb.x, v.w, acc[4][3]);
    acc[5][0] = fmaf(wb.y, v.x, acc[5][0]); acc[5][1] = fmaf(wb.y, v.y, acc[5][1]);
    acc[5][2] = fmaf(wb.y, v.z, acc[5][2]); acc[5][3] = fmaf(wb.y, v.w, acc[5][3]);
    acc[6][0] = fmaf(wb.z, v.x, acc[6][0]); acc[6][1] = fmaf(wb.z, v.y, acc[6][1]);
    acc[6][2] = fmaf(wb.z, v.z, acc[6][2]); acc[6][3] = fmaf(wb.z, v.w, acc[6][3]);
    acc[7][0] = fmaf(wb.w, v.x, acc[7][0]); acc[7][1] = fmaf(wb.w, v.y, acc[7][1]);
    acc[7][2] = fmaf(wb.w, v.z, acc[7][2]); acc[7][3] = fmaf(wb.w, v.w, acc[7][3]);
  }
  #pragma unroll
  for (int o = 0; o < 8; ++o) {
    int oc = oc0 + o;
    float inv = 1.f / sqrtf(vv[oc] + 1e-5f);
    float sc = g[oc]*inv;
    float4 r;
    r.x = silu_f((acc[o][0] - mm[oc])*sc + bb[oc]);
    r.y = silu_f((acc[o][1] - mm[oc])*sc + bb[oc]);
    r.z = silu_f((acc[o][2] - mm[oc])*sc + bb[oc]);
    r.w = silu_f((acc[o][3] - mm[oc])*sc + bb[oc]);
    *(float4*)(x1 + ((long)img*128 + oc)*HW4 + p0) = r;
  }
}

// ---------------- conv3: 3x3 128->128 SAME + BN+SiLU + BN_e+ReLU -----------
// 16x64 tile, 8 oc, 4 px/thread; grid 256 (1 block/CU). C3_ICS=4.
#define C3_TW 72
#define C3_TR 18
__global__ __launch_bounds__(256) void fm_conv3(
    const float* __restrict__ x1, const float* __restrict__ w,
    const float* __restrict__ g1, const float* __restrict__ b1,
    const float* __restrict__ m1, const float* __restrict__ v1,
    const float* __restrict__ ge, const float* __restrict__ be,
    const float* __restrict__ me, const float* __restrict__ ve,
    float* __restrict__ x2) {
  __shared__ float t[2][4][C3_TR*C3_TW];
  __shared__ float wl[2][4][9][8];
  int bid = blockIdx.x;
  int rt = bid & 3, ocg = (bid >> 2) & 15, img = bid >> 6;
  int oc0 = ocg * 8;
  int y0 = rt * 16;
  int tid = threadIdx.x;
  int ly = tid >> 4;
  int lx = tid & 15;
  int x0 = lx * 4;
  const float* xim = x1 + (long)img*128*HW4;

  int gbase[5][4];
  int lofs[5];
  #pragma unroll
  for (int t5 = 0; t5 < 5; ++t5) {
    int i = tid + 256*t5;
    if (i < 1224) {
      int q = i / 306, r = i - q*306;
      int row = r / 17, seg = r - row*17;
      int gy = y0 + row - 1;
      lofs[t5] = q*(C3_TR*C3_TW) + row*C3_TW + 4 + seg*4;
      #pragma unroll
      for (int e = 0; e < 4; ++e) {
        int x = seg*4 + e - 1;
        gbase[t5][e] = (gy >= 0 && gy < 64 && x >= 0 && x < 64)
                       ? (q*HW4 + gy*64 + x) : -1;
      }
    } else {
      lofs[t5] = -1;
      #pragma unroll
      for (int e = 0; e < 4; ++e) gbase[t5][e] = -1;
    }
  }
  int wg0 = -1, wl0 = 0, wg1 = -1, wl1 = 0;
  {
    int i = tid;
    if (i < 288) {
      int o = i & 7, k = (i >> 3) % 9, q = i / 72;
      wg0 = ((oc0 + o)*128 + q)*9 + k;
      wl0 = (q*9 + k)*8 + o;
    }
    i = tid + 256;
    if (i < 288) {
      int o = i & 7, k = (i >> 3) % 9, q = i / 72;
      wg1 = ((oc0 + o)*128 + q)*9 + k;
      wl1 = (q*9 + k)*8 + o;
    }
  }

  float4 sreg[5];
  float wreg0 = 0.f, wreg1 = 0.f;

  #define C3_LOAD(IC0) do {                                              \
    long icoff = (long)(IC0)*HW4;                                        \
    _Pragma("unroll")                                                    \
    for (int t5 = 0; t5 < 5; ++t5) {                                     \
      sreg[t5].x = (gbase[t5][0] >= 0) ? xim[icoff + gbase[t5][0]] : 0.f;\
      sreg[t5].y = (gbase[t5][1] >= 0) ? xim[icoff + gbase[t5][1]] : 0.f;\
      sreg[t5].z = (gbase[t5][2] >= 0) ? xim[icoff + gbase[t5][2]] : 0.f;\
      sreg[t5].w = (gbase[t5][3] >= 0) ? xim[icoff + gbase[t5][3]] : 0.f;\
    }                                                                    \
    if (wg0 >= 0) wreg0 = w[(long)(IC0)*9 + wg0];                        \
    if (wg1 >= 0) wreg1 = w[(long)(IC0)*9 + wg1];                        \
  } while (0)

  #define C3_WRITE(BUF) do {                                             \
    float* tb = &t[BUF][0][0];                                           \
    _Pragma("unroll")                                                    \
    for (int t5 = 0; t5 < 5; ++t5)                                       \
      if (lofs[t5] >= 0) *(float4*)(tb + lofs[t5]) = sreg[t5];           \
    if (wg0 >= 0) (&wl[BUF][0][0][0])[wl0] = wreg0;                      \
    if (wg1 >= 0) (&wl[BUF][0][0][0])[wl1] = wreg1;                      \
  } while (0)

  float acc[8][4];
  #pragma unroll
  for (int o = 0; o < 8; ++o)
    #pragma unroll
    for (int j = 0; j < 4; ++j) acc[o][j] = 0.f;

  C3_LOAD(0);
  C3_WRITE(0);
  __syncthreads();
  int pb = 0;
  for (int ic0 = 0; ic0 < 128; ic0 += 4) {
    if (ic0 + 4 < 128) C3_LOAD(ic0 + 4);
    #pragma unroll
    for (int q = 0; q < 4; ++q) {
      const float* tq = &t[pb][q][0];
      float n6[3][6];
      #pragma unroll
      for (int dy = 0; dy < 3; ++dy) {
        float4 a = *(const float4*)(tq + (ly + dy)*C3_TW + x0 + 4);
        float4 b2 = *(const float4*)(tq + (ly + dy)*C3_TW + x0 + 8);
        n6[dy][0] = a.x; n6[dy][1] = a.y; n6[dy][2] = a.z;
        n6[dy][3] = a.w; n6[dy][4] = b2.x; n6[dy][5] = b2.y;
      }
      #pragma unroll
      for (int k = 0; k < 9; ++k) {
        const int dy = k / 3, dx = k % 3;
        float4 wA = *(const float4*)&wl[pb][q][k][0];
        float4 wB = *(const float4*)&wl[pb][q][k][4];
        #pragma unroll
        for (int j = 0; j < 4; ++j) {
          float nv = n6[dy][dx + j];
          acc[0][j] = fmaf(wA.x, nv, acc[0][j]);
          acc[1][j] = fmaf(wA.y, nv, acc[1][j]);
          acc[2][j] = fmaf(wA.z, nv, acc[2][j]);
          acc[3][j] = fmaf(wA.w, nv, acc[3][j]);
          acc[4][j] = fmaf(wB.x, nv, acc[4][j]);
          acc[5][j] = fmaf(wB.y, nv, acc[5][j]);
          acc[6][j] = fmaf(wB.z, nv, acc[6][j]);
          acc[7][j] = fmaf(wB.w, nv, acc[7][j]);
        }
      }
    }
    if (ic0 + 4 < 128) C3_WRITE(pb ^ 1);
    __syncthreads();
    pb ^= 1;
  }
  int prow = (y0 + ly)*64 + x0;
  #pragma unroll
  for (int o = 0; o < 8; ++o) {
    int oc = oc0 + o;
    float inv1 = 1.f / sqrtf(v1[oc] + 1e-5f);
    float s1 = g1[oc]*inv1;
    float inve = 1.f / sqrtf(ve[oc] + 1e-5f);
    float s2 = ge[oc]*inve;
    float4 r;
    float y;
    y = silu_f((acc[o][0] - m1[oc])*s1 + b1[oc]); r.x = fmaxf((y - me[oc])*s2 + be[oc], 0.f);
    y = silu_f((acc[o][1] - m1[oc])*s1 + b1[oc]); r.y = fmaxf((y - me[oc])*s2 + be[oc], 0.f);
    y = silu_f((acc[o][2] - m1[oc])*s1 + b1[oc]); r.z = fmaxf((y - me[oc])*s2 + be[oc], 0.f);
    y = silu_f((acc[o][3] - m1[oc])*s1 + b1[oc]); r.w = fmaxf((y - me[oc])*s2 + be[oc], 0.f);
    *(float4*)(x2 + ((long)img*128 + oc)*HW4 + prow) = r;
  }
}

// ---------------- conv2: 1x1 128->64 + BN + SiLU -> desc (into d_out) ------
// 4 oc x 4 px per thread; grid 256.
__global__ __launch_bounds__(256) void fm_conv2(
    const float* __restrict__ x2, const float* __restrict__ w,
    const float* __restrict__ g, const float* __restrict__ bb,
    const float* __restrict__ mm, const float* __restrict__ vv,
    float* __restrict__ out) {
  __shared__ float wl[128*4];
  int bid = blockIdx.x;
  int pblk = bid & 3, ocg = (bid >> 2) & 15, img = bid >> 6;
  int oc0 = ocg * 4;
  int tid = threadIdx.x;
  for (int i = tid; i < 512; i += 256) {
    int o = i & 3, ic = i >> 2;
    wl[i] = w[(oc0 + o)*128 + ic];
  }
  __syncthreads();
  int p0 = pblk*1024 + tid*4;
  const float* src = x2 + (long)img*128*HW4;
  float acc[4][4];
  #pragma unroll
  for (int o = 0; o < 4; ++o)
    #pragma unroll
    for (int j = 0; j < 4; ++j) acc[o][j] = 0.f;
  #pragma unroll 4
  for (int ic = 0; ic < 128; ++ic) {
    float4 v = *(const float4*)(src + (long)ic*HW4 + p0);
    float4 wa = *(const float4*)&wl[ic*4];
    acc[0][0] = fmaf(wa.x, v.x, acc[0][0]); acc[0][1] = fmaf(wa.x, v.y, acc[0][1]);
    acc[0][2] = fmaf(wa.x, v.z, acc[0][2]); acc[0][3] = fmaf(wa.x, v.w, acc[0][3]);
    acc[1][0] = fmaf(wa.y, v.x, acc[1][0]); acc[1][1] = fmaf(wa.y, v.y, acc[1][1]);
    acc[1][2] = fmaf(wa.y, v.z, acc[1][2]); acc[1][3] = fmaf(wa.y, v.w, acc[1][3]);
    acc[2][0] = fmaf(wa.z, v.x, acc[2][0]); acc[2][1] = fmaf(wa.z, v.y, acc[2][1]);
    acc[2][2] = fmaf(wa.z, v.z, acc[2][2]); acc[2][3] = fmaf(wa.z, v.w, acc[2][3]);
    acc[3][0] = fmaf(wa.w, v.x, acc[3][0]); acc[3][1] = fmaf(wa.w, v.y, acc[3][1]);
    acc[3][2] = fmaf(wa.w, v.z, acc[3][2]); acc[3][3] = fmaf(wa.w, v.w, acc[3][3]);
  }
  #pragma unroll
  for (int o = 0; o < 4; ++o) {
    int oc = oc0 + o;
    float inv = 1.f / sqrtf(vv[oc] + 1e-5f);
    float sc = g[oc]*inv;
    float* dst = out + 18 + (long)img*262144 + (long)oc*HW4 + p0;
    #pragma unroll
    for (int j = 0; j < 4; ++j)
      dst[j] = silu_f((acc[o][j] - mm[oc])*sc + bb[oc]);
  }
}

// ---------------- sortf: resp + invn + bitonic top-512 + qn gather ---------
// 1 block per image, 1024 threads. Bitonic j<=2 passes folded into registers
// (identical compare-exchange network).
__global__ __launch_bounds__(1024) void fm_sortf(
    const float* __restrict__ out, float* __restrict__ invn,
    int* __restrict__ topidx, float* __restrict__ qn) {
  __shared__ unsigned long long keys[4096];
  int img = blockIdx.x, tid = threadIdx.x;
  const float* d = out + 18 + (long)img*262144;
  // resp (same c-ascending fmaf order as before) + invn + keys
  #pragma unroll
  for (int q = 0; q < 4; ++q) {
    int p = tid + q*1024;
    float s = 0.f;
    #pragma unroll
    for (int c = 0; c < 64; ++c) { float x = d[c*HW4 + p]; s = fmaf(x, x, s); }
    float r = sqrtf(s);
    invn[(long)img*HW4 + p] = 1.f / fmaxf(r, 1e-12f);
    keys[p] = ((unsigned long long)__float_as_uint(r) << 32) | (unsigned int)(4095 - p);
  }
  __syncthreads();
  for (int k = 2; k <= 4096; k <<= 1) {
    for (int j = k >> 1; j >= 4; j >>= 1) {
      for (int t = tid; t < 2048; t += 1024) {
        int i = 2*t - (t & (j - 1));
        int ixj = i ^ j;
        bool up = ((i & k) == 0);
        unsigned long long a = keys[i], b = keys[ixj];
        if ((a < b) == up) { keys[i] = b; keys[ixj] = a; }
      }
      __syncthreads();
    }
    // fused j=2 and j=1 passes in registers (same network)
    {
      int base = tid << 2;
      unsigned long long e0 = keys[base], e1 = keys[base+1];
      unsigned long long e2 = keys[base+2], e3 = keys[base+3];
      if (k == 2) {
        if (e0 < e1)  { unsigned long long t_ = e0; e0 = e1; e1 = t_; }  // up pair
        if (e2 >= e3) { unsigned long long t_ = e2; e2 = e3; e3 = t_; }  // down pair
      } else {
        bool up = ((base & k) == 0);
        if ((e0 < e2) == up) { unsigned long long t_ = e0; e0 = e2; e2 = t_; }
        if ((e1 < e3) == up) { unsigned long long t_ = e1; e1 = e3; e3 = t_; }
        if ((e0 < e1) == up) { unsigned long long t_ = e0; e0 = e1; e1 = t_; }
        if ((e2 < e3) == up) { unsigned long long t_ = e2; e2 = e3; e3 = t_; }
      }
      keys[base] = e0; keys[base+1] = e1; keys[base+2] = e2; keys[base+3] = e3;
    }
    __syncthreads();
  }
  if (tid < 512) topidx[img*512 + tid] = 4095 - (int)(keys[tid] & 0xFFFFFFFFull);
  // qn gather for rgb images (b = img < 2): qn[b][k][c] = d1[c][row]*invn[row]
  if (img < 2) {
    for (int e = tid; e < 512*64; e += 1024) {
      int k = e >> 6, c = e & 63;
      unsigned long long key = keys[k];
      int row = 4095 - (int)(key & 0xFFFFFFFFull);
      float r = __uint_as_float((unsigned int)(key >> 32));
      float iv = 1.f / fmaxf(r, 1e-12f);              // identical to invn value
      qn[((long)img*512 + k)*64 + c] = d[c*HW4 + row] * iv;
    }
  }
}

// ---------------- corr: tiled GEMM + online softmax partials ---------------
__global__ __launch_bounds__(256) void fm_corr(
    const float* __restrict__ out, const float* __restrict__ invn,
    const float* __restrict__ qn, float* __restrict__ part) {
  __shared__ float Qs[32*64];
  __shared__ float Ds[64*128];
  int tid = threadIdx.x;
  int tx = tid & 31, ty = tid >> 5;
  int jsplit = blockIdx.x;
  int kg = blockIdx.y;
  int b = blockIdx.z;
  int k0 = kg*32;
  const float* d2 = out + 18 + (long)(2 + b)*262144;
  const float* in2 = invn + (long)(2 + b)*HW4;
  {
    const float4* src = (const float4*)(qn + ((long)b*512 + k0)*64);
    float4* dst = (float4*)Qs;
    dst[tid] = src[tid];
    dst[tid + 256] = src[tid + 256];
  }
  float m[4], s[4];
  #pragma unroll
  for (int r = 0; r < 4; ++r) { m[r] = -INFINITY; s[r] = 0.f; }
  #pragma unroll
  for (int tile = 0; tile < 2; ++tile) {
    int j0 = jsplit*256 + tile*128;
    __syncthreads();
    {
      float4* dst = (float4*)Ds;
      #pragma unroll
      for (int t = 0; t < 8; ++t) {
        int i = tid + 256*t;
        int c = i >> 5, col4 = i & 31;
        dst[i] = *(const float4*)(d2 + (long)c*HW4 + j0 + col4*4);
      }
    }
    __syncthreads();
    float acc[4][4];
    #pragma unroll
    for (int r = 0; r < 4; ++r)
      #pragma unroll
      for (int cc = 0; cc < 4; ++cc) acc[r][cc] = 0.f;
    const float4* Ds4 = (const float4*)Ds;
    #pragma unroll 4
    for (int c = 0; c < 64; ++c) {
      float4 dv = Ds4[c*32 + tx];
      #pragma unroll
      for (int r = 0; r < 4; ++r) {
        float qv = Qs[(ty*4 + r)*64 + c];
        acc[r][0] = fmaf(qv, dv.x, acc[r][0]);
        acc[r][1] = fmaf(qv, dv.y, acc[r][1]);
        acc[r][2] = fmaf(qv, dv.z, acc[r][2]);
        acc[r][3] = fmaf(qv, dv.w, acc[r][3]);
      }
    }
    float i0 = in2[j0 + tx*4 + 0];
    float i1 = in2[j0 + tx*4 + 1];
    float i2 = in2[j0 + tx*4 + 2];
    float i3 = in2[j0 + tx*4 + 3];
    #pragma unroll
    for (int r = 0; r < 4; ++r) {
      float v0 = acc[r][0]*i0, v1 = acc[r][1]*i1, v2 = acc[r][2]*i2, v3 = acc[r][3]*i3;
      float vm = fmaxf(fmaxf(v0, v1), fmaxf(v2, v3));
      float nm = fmaxf(m[r], vm);
      s[r] = s[r]*expf(m[r] - nm) + expf(v0 - nm) + expf(v1 - nm) + expf(v2 - nm) + expf(v3 - nm);
      m[r] = nm;
    }
  }
  #pragma unroll
  for (int off = 1; off < 32; off <<= 1) {
    #pragma unroll
    for (int r = 0; r < 4; ++r) {
      float om = __shfl_xor(m[r], off);
      float os = __shfl_xor(s[r], off);
      float nm = fmaxf(m[r], om);
      s[r] = s[r]*expf(m[r] - nm) + os*expf(om - nm);
      m[r] = nm;
    }
  }
  if (tx == 0) {
    #pragma unroll
    for (int r = 0; r < 4; ++r) {
      long idx = (((long)b*512 + k0 + ty*4 + r)*NSPLIT + jsplit)*2;
      part[idx] = m[r];
      part[idx + 1] = s[r];
    }
  }
}

// ---------------- comb+build: merge partials, numerator, write A rows ------
__global__ __launch_bounds__(256) void fm_comb(
    const float* __restrict__ out, const float* __restrict__ invn,
    const int* __restrict__ topidx, const float* __restrict__ qn,
    const float* __restrict__ part, float* __restrict__ A) {
  int tid = threadIdx.x;
  int kp = blockIdx.x*4 + (tid >> 6);
  int lane = tid & 63;
  int b = kp >> 9, k = kp & 511;
  int col = topidx[(2 + b)*512 + k];
  const float* d2 = out + 18 + (long)(2 + b)*262144;
  float dot = qn[(long)kp*64 + lane] * d2[lane*HW4 + col];
  #pragma unroll
  for (int off = 1; off < 64; off <<= 1) dot += __shfl_xor(dot, off);
  if (lane == 0) {
    const float* pp = part + (long)kp*NSPLIT*2;
    float M = -INFINITY;
    #pragma unroll
    for (int i = 0; i < NSPLIT; ++i) M = fmaxf(M, pp[2*i]);
    float S = 0.f;
    #pragma unroll
    for (int i = 0; i < NSPLIT; ++i) S += pp[2*i + 1]*expf(pp[2*i] - M);
    float v = dot * invn[(long)(2 + b)*HW4 + col];
    float wt = expf(v - M)/S;
    // build the two DLT rows (same math as old fm_build)
    int i1 = topidx[b*512 + k];
    float x1 = (float)(i1 & 63) / 63.f * 2.f - 1.f;
    float y1 = (float)(i1 >> 6) / 63.f * 2.f - 1.f;
    float x2 = (float)(col & 63) / 63.f * 2.f - 1.f;
    float y2 = (float)(col >> 6) / 63.f * 2.f - 1.f;
    float* r = A + ((long)b*1024 + 2*k)*9;
    r[0] = x1*wt;  r[1] = y1*wt;  r[2] = wt;
    r[3] = 0.f;    r[4] = 0.f;    r[5] = 0.f;
    r[6] = (-x2*x1)*wt; r[7] = (-x2*y1)*wt; r[8] = (-x2)*wt;
    r[9]  = 0.f;   r[10] = 0.f;   r[11] = 0.f;
    r[12] = x1*wt; r[13] = y1*wt; r[14] = wt;
    r[15] = (-y2*x1)*wt; r[16] = (-y2*y1)*wt; r[17] = (-y2)*wt;
  }
}

// =========================== LAPACK ports ===================================
__device__ __forceinline__ void lap_slartg(float f, float g, float* cs, float* sn, float* r) {
  if (g == 0.f) { *cs = 1.f; *sn = 0.f; *r = f; }
  else if (f == 0.f) { *cs = 0.f; *sn = copysignf(1.f, g); *r = fabsf(g); }
  else {
    float d = sqrtf(f*f + g*g);
    *cs = fabsf(f) / d;
    *r = copysignf(d, f);
    *sn = g / (*r);
  }
}

__device__ __forceinline__ void lap_slas2(float f, float g, float h, float* ssmin, float* ssmax) {
  float fa = fabsf(f), ga = fabsf(g), ha = fabsf(h);
  float fhmn = fminf(fa, ha), fhmx = fmaxf(fa, ha);
  if (fhmn == 0.f) {
    *ssmin = 0.f;
    if (fhmx == 0.f) *ssmax = ga;
    else {
      float mx = fmaxf(fhmx, ga), mn = fminf(fhmx, ga);
      float q = mn / mx;
      *ssmax = mx * sqrtf(1.f + q*q);
    }
  } else {
    if (ga < fhmx) {
      float as_ = 1.f + fhmn/fhmx;
      float at_ = (fhmx - fhmn)/fhmx;
      float au = ga/fhmx; au = au*au;
      float c = 2.f / (sqrtf(as_*as_ + au) + sqrtf(at_*at_ + au));
      *ssmin = fhmn*c;
      *ssmax = fhmx/c;
    } else {
      float au = fhmx/ga;
      if (au == 0.f) { *ssmin = (fhmn*fhmx)/ga; *ssmax = ga; }
      else {
        float as_ = 1.f + fhmn/fhmx;
        float at_ = (fhmx - fhmn)/fhmx;
        float t1 = as_*au, t2 = at_*au;
        float c = 1.f / (sqrtf(1.f + t1*t1) + sqrtf(1.f + t2*t2));
        float smn = (fhmn*c)*au;
        *ssmin = smn + smn;
        *ssmax = ga/(c + c);
      }
    }
  }
}

__device__ __forceinline__ void lap_slasv2(float f, float g, float h, float* ssmin, float* ssmax,
                           float* snr, float* csr, float* snl, float* csl) {
  const float epsv = 5.9604645e-08f;
  float ft = f, fa = fabsf(f), ht = h, ha = fabsf(h);
  int pmax = 1;
  bool swap_ = (ha > fa);
  if (swap_) { pmax = 3; float tmp = ft; ft = ht; ht = tmp; tmp = fa; fa = ha; ha = tmp; }
  float gt = g, ga = fabsf(gt);
  float clt = 0.f, crt = 0.f, slt = 0.f, srt = 0.f;
  if (ga == 0.f) { *ssmin = ha; *ssmax = fa; clt = 1.f; crt = 1.f; slt = 0.f; srt = 0.f; }
  else {
    bool gasmal = true;
    if (ga > fa) {
      pmax = 2;
      if ((fa/ga) < epsv) {
        gasmal = false;
        *ssmax = ga;
        if (ha > 1.f) *ssmin = fa/(ga/ha); else *ssmin = (fa/ga)*ha;
        clt = 1.f; slt = ht/gt; srt = 1.f; crt = ft/gt;
      }
    }
    if (gasmal) {
      float d = fa - ha, l;
      if (d == fa) l = 1.f; else l = d/fa;
      float m_ = gt/ft;
      float t = 2.f - l;
      float mm2 = m_*m_, tt = t*t;
      float s = sqrtf(tt + mm2);
      float r_ = (l == 0.f) ? fabsf(m_) : sqrtf(l*l + mm2);
      float a = 0.5f*(s + r_);
      *ssmin = ha/a;
      *ssmax = fa*a;
      if (mm2 == 0.f) {
        if (l == 0.f) t = copysignf(2.f, ft)*copysignf(1.f, gt);
        else t = gt/copysignf(d, ft) + m_/t;
      } else {
        t = (m_/(s + t) + m_/(r_ + l))*(1.f + a);
      }
      float l2 = sqrtf(t*t + 4.f);
      crt = 2.f/l2;
      srt = t/l2;
      clt = (crt + srt*m_)/a;
      slt = (ht/ft)*srt/a;
    }
  }
  if (swap_) { *csl = srt; *snl = crt; *csr = slt; *snr = clt; }
  else { *csl = clt; *snl = slt; *csr = crt; *snr = srt; }
  float tsign = 1.f;
  if (pmax == 1) tsign = copysignf(1.f, *csr)*copysignf(1.f, *csl)*copysignf(1.f, f);
  if (pmax == 2) tsign = copysignf(1.f, *snr)*copysignf(1.f, *csl)*copysignf(1.f, g);
  if (pmax == 3) tsign = copysignf(1.f, *snr)*copysignf(1.f, *snl)*copysignf(1.f, h);
  *ssmax = copysignf(*ssmax, tsign);
  *ssmin = copysignf(*ssmin, tsign*copysignf(1.f, f)*copysignf(1.f, h));
}

// runtime-uniform-index register array helpers
__device__ __forceinline__ float get9(const float (&a)[9], int idx) {
  float v = a[0];
#pragma unroll
  for (int i = 1; i < 9; ++i) if (idx == i) v = a[i];
  return v;
}
__device__ __forceinline__ void set9(float (&a)[9], int idx, float val) {
#pragma unroll
  for (int i = 0; i < 9; ++i) if (idx == i) a[i] = val;
}

// register-resident sbdsqr, n=9 (see R5 notes)
__device__ __forceinline__ void bdsqr9_reg(float (&dd)[9], float (&ee)[9], float (&vt)[9]) {
  const float eps_ = 5.9604645e-08f;
  const float unfl_ = 1.17549435e-38f;
  const float tol_ = 10.f*eps_;
  float sminoa = fabsf(dd[0]);
  if (sminoa != 0.f) {
    float mu = sminoa;
    bool z = false;
#pragma unroll
    for (int i = 1; i < 9; ++i) {
      if (!z) {
        mu = fabsf(dd[i])*(mu/(mu + fabsf(ee[i-1])));
        sminoa = fminf(sminoa, mu);
        if (sminoa == 0.f) z = true;
      }
    }
  }
  sminoa = sminoa / 3.f;
  float thresh = fmaxf(tol_*sminoa, 486.f*unfl_);
  int m = 9, iter = 0, oldll = -1, oldm = -1, idir = 0;
  float sminl = 0.f;
  int guard = 0;
  while (guard++ < 2000) {
    if (m <= 1) break;
    if (iter > 486) break;
    float smax = fabsf(get9(dd, m-1));
    int ll = 0; bool split = false;
#pragma unroll
    for (int l2 = 8; l2 >= 1; --l2) {
      if (l2 <= m - 1 && !split) {
        float abss = fabsf(dd[l2-1]);
        float abse = fabsf(ee[l2-1]);
        if (abse <= thresh) { ll = l2; split = true; }
        else smax = fmaxf(smax, fmaxf(abss, abse));
      }
    }
    if (split) {
      set9(ee, ll-1, 0.f);
      if (ll == m - 1) { m = m - 1; continue; }
    } else ll = 0;
    ll = ll + 1;
    if (ll == m - 1) {
      float d1 = get9(dd, m-2), e1 = get9(ee, m-2), d2v = get9(dd, m-1);
      float sigmn, sigmx, sinr, cosr, sinl_, cosl_;
      lap_slasv2(d1, e1, d2v, &sigmn, &sigmx, &sinr, &cosr, &sinl_, &cosl_);
      set9(dd, m-2, sigmx); set9(ee, m-2, 0.f); set9(dd, m-1, sigmn);
      float xt = get9(vt, m-2), yt = get9(vt, m-1);
      set9(vt, m-2, cosr*xt + sinr*yt);
      set9(vt, m-1, cosr*yt - sinr*xt);
      m -= 2; continue;
    }
    if (ll > oldm || m < oldll)
      idir = (fabsf(get9(dd, ll-1)) >= fabsf(get9(dd, m-1))) ? 1 : 2;
    bool conv = false;
    if (idir == 1) {
      if (fabsf(get9(ee, m-2)) <= tol_*fabsf(get9(dd, m-1))) { set9(ee, m-2, 0.f); continue; }
      float mu = fabsf(get9(dd, ll-1));
      sminl = mu;
#pragma unroll
      for (int lll = 1; lll <= 8; ++lll) {
        if (lll >= ll && lll <= m - 1 && !conv) {
          if (fabsf(ee[lll-1]) <= tol_*mu) { ee[lll-1] = 0.f; conv = true; }
          else {
            mu = fabsf(dd[lll])*(mu/(mu + fabsf(ee[lll-1])));
            sminl = fminf(sminl, mu);
          }
        }
      }
    } else {
      if (fabsf(get9(ee, ll-1)) <= tol_*fabsf(get9(dd, ll-1))) { set9(ee, ll-1, 0.f); continue; }
      float mu = fabsf(get9(dd, m-1));
      sminl = mu;
#pragma unroll
      for (int lll = 8; lll >= 1; --lll) {
        if (lll <= m - 1 && lll >= ll && !conv) {
          if (fabsf(ee[lll-1]) <= tol_*mu) { ee[lll-1] = 0.f; conv = true; }
          else {
            mu = fabsf(dd[lll-1])*(mu/(mu + fabsf(ee[lll-1])));
            sminl = fminf(sminl, mu);
          }
        }
      }
    }
    if (conv) continue;
    oldll = ll; oldm = m;
    float shift = 0.f, rdum;
    if (!(9.f*tol_*(sminl/smax) <= fmaxf(eps_, 0.01f*tol_))) {
      float sll;
      if (idir == 1) { sll = fabsf(get9(dd, ll-1)); lap_slas2(get9(dd, m-2), get9(ee, m-2), get9(dd, m-1), &shift, &rdum); }
      else           { sll = fabsf(get9(dd, m-1));  lap_slas2(get9(dd, ll-1), get9(ee, ll-1), get9(dd, ll), &shift, &rdum); }
      if (sll > 0.f) { float q = shift/sll; if (q*q < eps_) shift = 0.f; }
    }
    iter += m - ll;
    if (shift == 0.f) {
      if (idir == 1) {
        float cs = 1.f, oldcs = 1.f, sn = 0.f, oldsn = 0.f, r;
#pragma unroll
        for (int i = 1; i <= 8; ++i) {
          if (i >= ll && i <= m - 1) {
            lap_slartg(dd[i-1]*cs, ee[i-1], &cs, &sn, &r);
            if (i >= 2 && i > ll) ee[i-2] = oldsn*r;
            float dn;
            lap_slartg(oldcs*r, dd[i]*sn, &oldcs, &oldsn, &dn);
            dd[i-1] = dn;
            float t = vt[i]; vt[i] = cs*t - sn*vt[i-1]; vt[i-1] = sn*t + cs*vt[i-1];
          }
        }
        float h2 = get9(dd, m-1)*cs;
        set9(dd, m-1, h2*oldcs);
        set9(ee, m-2, h2*oldsn);
        if (fabsf(get9(ee, m-2)) <= thresh) set9(ee, m-2, 0.f);
      } else {
        float cs = 1.f, oldcs = 1.f, sn = 0.f, oldsn = 0.f, r;
#pragma unroll
        for (int i = 9; i >= 2; --i) {
          if (i <= m && i >= ll + 1) {
            lap_slartg(dd[i-1]*cs, ee[i-2], &cs, &sn, &r);
            if (i < m) ee[i-1] = oldsn*r;
            float dn;
            lap_slartg(oldcs*r, dd[i-2]*sn, &oldcs, &oldsn, &dn);
            dd[i-1] = dn;
            float c2 = oldcs, s2 = -oldsn;
            float t = vt[i-1]; vt[i-1] = c2*t - s2*vt[i-2]; vt[i-2] = s2*t + c2*vt[i-2];
          }
        }
        float h2 = get9(dd, ll-1)*cs;
        set9(dd, ll-1, h2*oldcs);
        set9(ee, ll-1, h2*oldsn);
        if (fabsf(get9(ee, ll-1)) <= thresh) set9(ee, ll-1, 0.f);
      }
    } else {
      if (idir == 1) {
        float d0 = get9(dd, ll-1);
        float f2 = (fabsf(d0) - shift)*(copysignf(1.f, d0) + shift/d0);
        float g2 = get9(ee, ll-1);
#pragma unroll
        for (int i = 1; i <= 8; ++i) {
          if (i >= ll && i <= m - 1) {
            float cr, sr, cl, sl, r;
            lap_slartg(f2, g2, &cr, &sr, &r);
            if (i >= 2 && i > ll) ee[i-2] = r;
            f2 = cr*dd[i-1] + sr*ee[i-1];
            ee[i-1] = cr*ee[i-1] - sr*dd[i-1];
            g2 = sr*dd[i];
            dd[i] = cr*dd[i];
            lap_slartg(f2, g2, &cl, &sl, &r);
            dd[i-1] = r;
            f2 = cl*ee[i-1] + sl*dd[i];
            dd[i] = cl*dd[i] - sl*ee[i-1];
            if (i < m - 1) { g2 = sl*ee[i]; ee[i] = cl*ee[i]; }
            float t = vt[i]; vt[i] = cr*t - sr*vt[i-1]; vt[i-1] = sr*t + cr*vt[i-1];
          }
        }
        set9(ee, m-2, f2);
        if (fabsf(get9(ee, m-2)) <= thresh) set9(ee, m-2, 0.f);
      } else {
        float dm = get9(dd, m-1);
        float f2 = (fabsf(dm) - shift)*(copysignf(1.f, dm) + shift/dm);
        float g2 = get9(ee, m-2);
#pragma unroll
        for (int i = 9; i >= 2; --i) {
          if (i <= m && i >= ll + 1) {
            float cr, sr, cl, sl, r;
            lap_slartg(f2, g2, &cr, &sr, &r);
            if (i < m) ee[i-1] = r;
            f2 = cr*dd[i-1] + sr*ee[i-2];
            ee[i-2] = cr*ee[i-2] - sr*dd[i-1];
            g2 = sr*dd[i-2];
            dd[i-2] = cr*dd[i-2];
            lap_slartg(f2, g2, &cl, &sl, &r);
            dd[i-1] = r;
            f2 = cl*ee[i-2] + sl*dd[i-2];
            dd[i-2] = cl*dd[i-2] - sl*ee[i-2];
            if (i >= 3 && i > ll + 1) { g2 = sl*ee[i-3]; ee[i-3] = cl*ee[i-3]; }
            float c2 = cl, s2 = -sl;
            float t = vt[i-1]; vt[i-1] = c2*t - s2*vt[i-2]; vt[i-2] = s2*t + c2*vt[i-2];
          }
        }
        set9(ee, ll-1, f2);
        if (fabsf(get9(ee, ll-1)) <= thresh) set9(ee, ll-1, 0.f);
      }
    }
  }
#pragma unroll
  for (int i = 0; i < 9; ++i) {
    if (dd[i] < 0.f) { dd[i] = -dd[i]; vt[i] = -vt[i]; }
  }
#pragma unroll
  for (int i = 1; i <= 8; ++i) {
    int isub = 1; float smin2 = dd[0];
#pragma unroll
    for (int j = 2; j <= 9; ++j) {
      if (j <= 10 - i) {
        if (dd[j-1] <= smin2) { isub = j; smin2 = dd[j-1]; }
      }
    }
    const int tgt = 10 - i;
    if (isub != tgt) {
      set9(dd, isub-1, dd[tgt-1]);
      dd[tgt-1] = smin2;
      float tv = get9(vt, isub-1);
      set9(vt, isub-1, vt[tgt-1]);
      vt[tgt-1] = tv;
    }
  }
}

// ---------------- SVD kernel: batched-larf QR + register gebrd/bdsqr -------
__global__ __launch_bounds__(256) void fm_svd(
    const float* __restrict__ Aglob, float* __restrict__ outH) {
  __shared__ float As[1024*9];
  __shared__ float wred[4][12];
  __shared__ float bc[4];
  int b = blockIdx.x, tid = threadIdx.x;
  int wv = tid >> 6, ln = tid & 63;
  const float* Ab = Aglob + (long)b*9216;
  {
    const float4* s4 = (const float4*)Ab;
    float4* d4 = (float4*)As;
#pragma unroll
    for (int t = 0; t < 9; ++t) d4[tid + 256*t] = s4[tid + 256*t];
  }
  __syncthreads();
  for (int k = 0; k < 9; ++k) {
    float ps = 0.f;
    for (int r = k + 1 + tid; r < 1024; r += 256) {
      float x = As[r*9 + k]; ps = fmaf(x, x, ps);
    }
#pragma unroll
    for (int off = 1; off < 64; off <<= 1) ps += __shfl_xor(ps, off);
    if (ln == 0) wred[wv][8] = ps;
    __syncthreads();
    if (tid == 0) {
      float ssq = wred[0][8] + wred[1][8] + wred[2][8] + wred[3][8];
      float alpha = As[k*9 + k];
      float tau = 0.f, sc = 0.f, beta = alpha;
      if (ssq != 0.f) {
        beta = -copysignf(sqrtf(alpha*alpha + ssq), alpha);
        tau = (beta - alpha)/beta;
        sc = 1.f/(alpha - beta);
      }
      bc[0] = tau; bc[1] = sc; bc[2] = beta;
    }
    __syncthreads();
    float tau = bc[0], sc = bc[1];
    if (tau != 0.f) {
      for (int r = k + 1 + tid; r < 1024; r += 256) As[r*9 + k] *= sc;
    }
    __syncthreads();
    if (tau != 0.f) {
      float pd[8];
#pragma unroll
      for (int jj = 0; jj < 8; ++jj) pd[jj] = 0.f;
      for (int r = k + 1 + tid; r < 1024; r += 256) {
        float vk = As[r*9 + k];
#pragma unroll
        for (int jj = 0; jj < 8; ++jj) {
          int j = k + 1 + jj;
          if (j < 9) pd[jj] = fmaf(vk, As[r*9 + j], pd[jj]);
        }
      }
#pragma unroll
      for (int off = 1; off < 64; off <<= 1) {
#pragma unroll
        for (int jj = 0; jj < 8; ++jj) pd[jj] += __shfl_xor(pd[jj], off);
      }
      if (ln == 0) {
#pragma unroll
        for (int jj = 0; jj < 8; ++jj) wred[wv][jj] = pd[jj];
      }
      __syncthreads();
      float sj[8];
#pragma unroll
      for (int jj = 0; jj < 8; ++jj) {
        int j = k + 1 + jj;
        float v = 0.f;
        if (j < 9)
          v = (wred[0][jj] + wred[1][jj] + wred[2][jj] + wred[3][jj] + As[k*9 + j]) * tau;
        sj[jj] = v;
      }
      for (int r = k + 1 + tid; r < 1024; r += 256) {
        float vk = As[r*9 + k];
#pragma unroll
        for (int jj = 0; jj < 8; ++jj) {
          int j = k + 1 + jj;
          if (j < 9) As[r*9 + j] -= sj[jj]*vk;
        }
      }
      __syncthreads();
      if (tid == 0) {
#pragma unroll
        for (int jj = 0; jj < 8; ++jj) {
          int j = k + 1 + jj;
          if (j < 9) As[k*9 + j] -= sj[jj];
        }
      }
    }
    if (tid == 0) As[k*9 + k] = bc[2];
    __syncthreads();
  }
  if (tid < 64) {
    float R[9][9];
#pragma unroll
    for (int i = 0; i < 9; ++i)
#pragma unroll
      for (int j = 0; j < 9; ++j)
        R[i][j] = (j >= i) ? As[i*9 + j] : 0.f;
    float dd[9], ee[9], taupv[8], pt8[9];
    ee[8] = 0.f;
#pragma unroll
    for (int i = 0; i < 9; ++i) {
      float alpha = R[i][i];
      float ssq = 0.f;
#pragma unroll
      for (int r2 = i + 1; r2 < 9; ++r2) ssq += R[r2][i]*R[r2][i];
      float tauq = 0.f, beta = alpha;
      if (ssq != 0.f) {
        beta = -copysignf(sqrtf(alpha*alpha + ssq), alpha);
        tauq = (beta - alpha)/beta;
        float scq = 1.f/(alpha - beta);
#pragma unroll
        for (int r2 = i + 1; r2 < 9; ++r2) R[r2][i] *= scq;
      }
      dd[i] = beta;
      if (tauq != 0.f) {
#pragma unroll
        for (int j = i + 1; j < 9; ++j) {
          float s = R[i][j];
#pragma unroll
          for (int r2 = i + 1; r2 < 9; ++r2) s += R[r2][i]*R[r2][j];
          s *= tauq;
          R[i][j] -= s;
#pragma unroll
          for (int r2 = i + 1; r2 < 9; ++r2) R[r2][j] -= s*R[r2][i];
        }
      }
      if (i < 8) {
        float alpha2 = R[i][i+1];
        float ssq2 = 0.f;
#pragma unroll
        for (int c = i + 2; c < 9; ++c) ssq2 += R[i][c]*R[i][c];
        float tp = 0.f, beta2 = alpha2;
        if (ssq2 != 0.f) {
          beta2 = -copysignf(sqrtf(alpha2*alpha2 + ssq2), alpha2);
          tp = (beta2 - alpha2)/beta2;
          float scp = 1.f/(alpha2 - beta2);
#pragma unroll
          for (int c = i + 2; c < 9; ++c) R[i][c] *= scp;
        }
        ee[i] = beta2;
        taupv[i] = tp;
        if (tp != 0.f) {
#pragma unroll
          for (int r2 = i + 1; r2 < 9; ++r2) {
            float s = R[r2][i+1];
#pragma unroll
            for (int c = i + 2; c < 9; ++c) s += R[i][c]*R[r2][c];
            s *= tp;
            R[r2][i+1] -= s;
#pragma unroll
            for (int c = i + 2; c < 9; ++c) R[r2][c] -= s*R[i][c];
          }
        }
      }
    }
#pragma unroll
    for (int i = 0; i < 9; ++i) pt8[i] = (i == 8) ? 1.f : 0.f;
#pragma unroll
    for (int i = 0; i < 8; ++i) {
      float tp = taupv[i];
      if (tp != 0.f) {
        float s = pt8[i+1];
#pragma unroll
        for (int r2 = i + 2; r2 < 9; ++r2) s += R[i][r2]*pt8[r2];
        s *= tp;
        pt8[i+1] -= s;
#pragma unroll
        for (int r2 = i + 2; r2 < 9; ++r2) pt8[r2] -= s*R[i][r2];
      }
    }
    float vt[9];
#pragma unroll
    for (int i = 0; i < 9; ++i) vt[i] = (i == tid) ? 1.f : 0.f;
    bdsqr9_reg(dd, ee, vt);
    float p8 = (tid < 9) ? get9(pt8, tid) : 0.f;
    float h[9];
#pragma unroll
    for (int i = 0; i < 9; ++i) h[i] = vt[i]*p8;
#pragma unroll
    for (int off = 1; off < 16; off <<= 1) {
#pragma unroll
      for (int i = 0; i < 9; ++i) h[i] += __shfl_xor(h[i], off);
    }
    if (tid == 0) {
#pragma unroll
      for (int i = 0; i < 9; ++i) outH[b*9 + i] = h[i];
    }
  }
}

// ===========================================================================
extern "C" void kernel_launch(void* const* d_in, const int* in_sizes, int n_in,
                              void* d_out, int out_size, void* d_ws, size_t ws_size,
                              hipStream_t stream) {
  const float* rgb  = (const float*)d_in[0];
  const float* ir   = (const float*)d_in[1];
  const float* w_dr = (const float*)d_in[2];
  const float* g_dr = (const float*)d_in[3];
  const float* b_dr = (const float*)d_in[4];
  const float* m_dr = (const float*)d_in[5];
  const float* v_dr = (const float*)d_in[6];
  const float* w_d1 = (const float*)d_in[7];
  const float* g_d1 = (const float*)d_in[8];
  const float* b_d1 = (const float*)d_in[9];
  const float* m_d1 = (const float*)d_in[10];
  const float* v_d1 = (const float*)d_in[11];
  const float* g_e  = (const float*)d_in[12];
  const float* b_e  = (const float*)d_in[13];
  const float* m_e  = (const float*)d_in[14];
  const float* v_e  = (const float*)d_in[15];
  const float* w_d2 = (const float*)d_in[16];
  const float* g_d2 = (const float*)d_in[17];
  const float* b_d2 = (const float*)d_in[18];
  const float* m_d2 = (const float*)d_in[19];
  const float* v_d2 = (const float*)d_in[20];

  float* out = (float*)d_out;
  float* ws  = (float*)d_ws;
  float* x1   = ws + OFF_X1;
  float* x2   = ws + OFF_X2;
  float* invn = ws + OFF_INVN;
  int*   topi = (int*)(ws + OFF_TOPI);
  float* Amat = ws + OFF_A;
  float* qn   = ws + OFF_QN;     // aliases x1 (free after conv3)
  float* part = ws + OFF_PART;   // aliases x1

  fm_conv1<<<256, 256, 0, stream>>>(rgb, ir, w_dr, g_dr, b_dr, m_dr, v_dr, x1);
  fm_conv3<<<256, 256, 0, stream>>>(x1, w_d1, g_d1, b_d1, m_d1, v_d1,
                                    g_e, b_e, m_e, v_e, x2);
  fm_conv2<<<256, 256, 0, stream>>>(x2, w_d2, g_d2, b_d2, m_d2, v_d2, out);
  fm_sortf<<<NIMG, 1024, 0, stream>>>(out, invn, topi, qn);
  fm_corr<<<dim3(NSPLIT, 16, 2), 256, 0, stream>>>(out, invn, qn, part);
  fm_comb<<<256, 256, 0, stream>>>(out, invn, topi, qn, part, Amat);
  fm_svd<<<2, 256, 0, stream>>>(Amat, out);
}

// Round 16
// 384.967 us; speedup vs baseline: 1.1382x; 1.1382x over previous
//
#include <hip/hip_runtime.h>
#include <math.h>

// ---------------------------------------------------------------------------
// FeatureMatching: conv tower -> top-k keypoints -> softmax corr gather ->
// weighted DLT -> LAPACK-faithful sgesdd(QR path) SVD for H = Vh[:,:,-1].
// All f32. B=2, C=256, H=W=64, HW=4096, K=512.
// R16 = R11 (best measured: 385.9us total, conv3 140us, absmax 9.77e-4).
//   conv3: R4 inner loop (8oc x 4px, b128 nbhd + b128 broadcast weights,
//   C3_ICS=4, grid 256, LDS-pipe bound at ~51% VALU). R5 register SVD.
//   R2 corr pipeline. Fusion (R12) regressed; widening (R8/R10) regressed;
//   scalar weights (R3/R9) regressed; shfl nbhd (R7) regressed.
// ---------------------------------------------------------------------------

#define HW4 4096
#define NIMG 4   // imgs 0,1 = rgb batches; 2,3 = ir batches

// ws layout (floats)
#define OFF_X1   0L
#define OFF_X2   (OFF_X1 + 4L*128*4096)
#define OFF_RESP (OFF_X2 + 4L*128*4096)
#define OFF_INVN (OFF_RESP + 4L*4096)
#define OFF_TOPI (OFF_INVN + 4L*4096)      /* 4*512 ints */
#define OFF_WTS  (OFF_TOPI + 4L*512)
#define OFF_A    (OFF_WTS + 2L*512)
#define OFF_QN   OFF_X1
#define OFF_PART (OFF_X1 + 65536L)

#define NSPLIT 16   // j-splits in fm_corr (each covers 256 cols)

__device__ __forceinline__ float silu_f(float y) { return y / (1.f + expf(-y)); }

// ---------------- conv1: 1x1 256->128 + BN + SiLU --------------------------
// 8 oc x 4 px per thread; grid 256.
__global__ __launch_bounds__(256) void fm_conv1(
    const float* __restrict__ rgb, const float* __restrict__ ir,
    const float* __restrict__ w, const float* __restrict__ g,
    const float* __restrict__ bb, const float* __restrict__ mm,
    const float* __restrict__ vv, float* __restrict__ x1) {
  __shared__ float wl[256*8];   // [ic][o]
  int bid = blockIdx.x;
  int pblk = bid & 3, ocg = (bid >> 2) & 15, img = bid >> 6;
  int oc0 = ocg * 8;
  int tid = threadIdx.x;
  const float* src = (img < 2) ? (rgb + (long)img*256*HW4) : (ir + (long)(img-2)*256*HW4);
  for (int i = tid; i < 2048; i += 256) {
    int o = i & 7, ic = i >> 3;
    wl[i] = w[(oc0 + o)*256 + ic];
  }
  __syncthreads();
  int p0 = pblk*1024 + tid*4;
  float acc[8][4];
  #pragma unroll
  for (int o = 0; o < 8; ++o)
    #pragma unroll
    for (int j = 0; j < 4; ++j) acc[o][j] = 0.f;
  #pragma unroll 4
  for (int ic = 0; ic < 256; ++ic) {
    float4 v = *(const float4*)(src + (long)ic*HW4 + p0);
    float4 wa = *(const float4*)&wl[ic*8];
    float4 wb = *(const float4*)&wl[ic*8 + 4];
    acc[0][0] = fmaf(wa.x, v.x, acc[0][0]); acc[0][1] = fmaf(wa.x, v.y, acc[0][1]);
    acc[0][2] = fmaf(wa.x, v.z, acc[0][2]); acc[0][3] = fmaf(wa.x, v.w, acc[0][3]);
    acc[1][0] = fmaf(wa.y, v.x, acc[1][0]); acc[1][1] = fmaf(wa.y, v.y, acc[1][1]);
    acc[1][2] = fmaf(wa.y, v.z, acc[1][2]); acc[1][3] = fmaf(wa.y, v.w, acc[1][3]);
    acc[2][0] = fmaf(wa.z, v.x, acc[2][0]); acc[2][1] = fmaf(wa.z, v.y, acc[2][1]);
    acc[2][2] = fmaf(wa.z, v.z, acc[2][2]); acc[2][3] = fmaf(wa.z, v.w, acc[2][3]);
    acc[3][0] = fmaf(wa.w, v.x, acc[3][0]); acc[3][1] = fmaf(wa.w, v.y, acc[3][1]);
    acc[3][2] = fmaf(wa.w, v.z, acc[3][2]); acc[3][3] = fmaf(wa.w, v.w, acc[3][3]);
    acc[4][0] = fmaf(wb.x, v.x, acc[4][0]); acc[4][1] = fmaf(wb.x, v.y, acc[4][1]);
    acc[4][2] = fmaf(wb.x, v.z, acc[4][2]); acc[4][3] = fmaf(wb.x, v.w, acc[4][3]);
    acc[5][0] = fmaf(wb.y, v.x, acc[5][0]); acc[5][1] = fmaf(wb.y, v.y, acc[5][1]);
    acc[5][2] = fmaf(wb.y, v.z, acc[5][2]); acc[5][3] = fmaf(wb.y, v.w, acc[5][3]);
    acc[6][0] = fmaf(wb.z, v.x, acc[6][0]); acc[6][1] = fmaf(wb.z, v.y, acc[6][1]);
    acc[6][2] = fmaf(wb.z, v.z, acc[6][2]); acc[6][3] = fmaf(wb.z, v.w, acc[6][3]);
    acc[7][0] = fmaf(wb.w, v.x, acc[7][0]); acc[7][1] = fmaf(wb.w, v.y, acc[7][1]);
    acc[7][2] = fmaf(wb.w, v.z, acc[7][2]); acc[7][3] = fmaf(wb.w, v.w, acc[7][3]);
  }
  #pragma unroll
  for (int o = 0; o < 8; ++o) {
    int oc = oc0 + o;
    float inv = 1.f / sqrtf(vv[oc] + 1e-5f);
    float sc = g[oc]*inv;
    float4 r;
    r.x = silu_f((acc[o][0] - mm[oc])*sc + bb[oc]);
    r.y = silu_f((acc[o][1] - mm[oc])*sc + bb[oc]);
    r.z = silu_f((acc[o][2] - mm[oc])*sc + bb[oc]);
    r.w = silu_f((acc[o][3] - mm[oc])*sc + bb[oc]);
    *(float4*)(x1 + ((long)img*128 + oc)*HW4 + p0) = r;
  }
}

// ---------------- conv3: 3x3 128->128 SAME + BN+SiLU + BN_e+ReLU -----------
// 16x64 tile, 8 oc, 4 px/thread; grid 256 (1 block/CU). C3_ICS=4.
#define C3_TW 72
#define C3_TR 18
__global__ __launch_bounds__(256) void fm_conv3(
    const float* __restrict__ x1, const float* __restrict__ w,
    const float* __restrict__ g1, const float* __restrict__ b1,
    const float* __restrict__ m1, const float* __restrict__ v1,
    const float* __restrict__ ge, const float* __restrict__ be,
    const float* __restrict__ me, const float* __restrict__ ve,
    float* __restrict__ x2) {
  __shared__ float t[2][4][C3_TR*C3_TW];
  __shared__ float wl[2][4][9][8];
  int bid = blockIdx.x;
  int rt = bid & 3, ocg = (bid >> 2) & 15, img = bid >> 6;
  int oc0 = ocg * 8;
  int y0 = rt * 16;
  int tid = threadIdx.x;
  int ly = tid >> 4;
  int lx = tid & 15;
  int x0 = lx * 4;
  const float* xim = x1 + (long)img*128*HW4;

  int gbase[5][4];
  int lofs[5];
  #pragma unroll
  for (int t5 = 0; t5 < 5; ++t5) {
    int i = tid + 256*t5;
    if (i < 1224) {
      int q = i / 306, r = i - q*306;
      int row = r / 17, seg = r - row*17;
      int gy = y0 + row - 1;
      lofs[t5] = q*(C3_TR*C3_TW) + row*C3_TW + 4 + seg*4;
      #pragma unroll
      for (int e = 0; e < 4; ++e) {
        int x = seg*4 + e - 1;
        gbase[t5][e] = (gy >= 0 && gy < 64 && x >= 0 && x < 64)
                       ? (q*HW4 + gy*64 + x) : -1;
      }
    } else {
      lofs[t5] = -1;
      #pragma unroll
      for (int e = 0; e < 4; ++e) gbase[t5][e] = -1;
    }
  }
  int wg0 = -1, wl0 = 0, wg1 = -1, wl1 = 0;
  {
    int i = tid;
    if (i < 288) {
      int o = i & 7, k = (i >> 3) % 9, q = i / 72;
      wg0 = ((oc0 + o)*128 + q)*9 + k;
      wl0 = (q*9 + k)*8 + o;
    }
    i = tid + 256;
    if (i < 288) {
      int o = i & 7, k = (i >> 3) % 9, q = i / 72;
      wg1 = ((oc0 + o)*128 + q)*9 + k;
      wl1 = (q*9 + k)*8 + o;
    }
  }

  float4 sreg[5];
  float wreg0 = 0.f, wreg1 = 0.f;

  #define C3_LOAD(IC0) do {                                              \
    long icoff = (long)(IC0)*HW4;                                        \
    _Pragma("unroll")                                                    \
    for (int t5 = 0; t5 < 5; ++t5) {                                     \
      sreg[t5].x = (gbase[t5][0] >= 0) ? xim[icoff + gbase[t5][0]] : 0.f;\
      sreg[t5].y = (gbase[t5][1] >= 0) ? xim[icoff + gbase[t5][1]] : 0.f;\
      sreg[t5].z = (gbase[t5][2] >= 0) ? xim[icoff + gbase[t5][2]] : 0.f;\
      sreg[t5].w = (gbase[t5][3] >= 0) ? xim[icoff + gbase[t5][3]] : 0.f;\
    }                                                                    \
    if (wg0 >= 0) wreg0 = w[(long)(IC0)*9 + wg0];                        \
    if (wg1 >= 0) wreg1 = w[(long)(IC0)*9 + wg1];                        \
  } while (0)

  #define C3_WRITE(BUF) do {                                             \
    float* tb = &t[BUF][0][0];                                           \
    _Pragma("unroll")                                                    \
    for (int t5 = 0; t5 < 5; ++t5)                                       \
      if (lofs[t5] >= 0) *(float4*)(tb + lofs[t5]) = sreg[t5];           \
    if (wg0 >= 0) (&wl[BUF][0][0][0])[wl0] = wreg0;                      \
    if (wg1 >= 0) (&wl[BUF][0][0][0])[wl1] = wreg1;                      \
  } while (0)

  float acc[8][4];
  #pragma unroll
  for (int o = 0; o < 8; ++o)
    #pragma unroll
    for (int j = 0; j < 4; ++j) acc[o][j] = 0.f;

  C3_LOAD(0);
  C3_WRITE(0);
  __syncthreads();
  int pb = 0;
  for (int ic0 = 0; ic0 < 128; ic0 += 4) {
    if (ic0 + 4 < 128) C3_LOAD(ic0 + 4);
    #pragma unroll
    for (int q = 0; q < 4; ++q) {
      const float* tq = &t[pb][q][0];
      float n6[3][6];
      #pragma unroll
      for (int dy = 0; dy < 3; ++dy) {
        float4 a = *(const float4*)(tq + (ly + dy)*C3_TW + x0 + 4);
        float4 b2 = *(const float4*)(tq + (ly + dy)*C3_TW + x0 + 8);
        n6[dy][0] = a.x; n6[dy][1] = a.y; n6[dy][2] = a.z;
        n6[dy][3] = a.w; n6[dy][4] = b2.x; n6[dy][5] = b2.y;
      }
      #pragma unroll
      for (int k = 0; k < 9; ++k) {
        const int dy = k / 3, dx = k % 3;
        float4 wA = *(const float4*)&wl[pb][q][k][0];
        float4 wB = *(const float4*)&wl[pb][q][k][4];
        #pragma unroll
        for (int j = 0; j < 4; ++j) {
          float nv = n6[dy][dx + j];
          acc[0][j] = fmaf(wA.x, nv, acc[0][j]);
          acc[1][j] = fmaf(wA.y, nv, acc[1][j]);
          acc[2][j] = fmaf(wA.z, nv, acc[2][j]);
          acc[3][j] = fmaf(wA.w, nv, acc[3][j]);
          acc[4][j] = fmaf(wB.x, nv, acc[4][j]);
          acc[5][j] = fmaf(wB.y, nv, acc[5][j]);
          acc[6][j] = fmaf(wB.z, nv, acc[6][j]);
          acc[7][j] = fmaf(wB.w, nv, acc[7][j]);
        }
      }
    }
    if (ic0 + 4 < 128) C3_WRITE(pb ^ 1);
    __syncthreads();
    pb ^= 1;
  }
  int prow = (y0 + ly)*64 + x0;
  #pragma unroll
  for (int o = 0; o < 8; ++o) {
    int oc = oc0 + o;
    float inv1 = 1.f / sqrtf(v1[oc] + 1e-5f);
    float s1 = g1[oc]*inv1;
    float inve = 1.f / sqrtf(ve[oc] + 1e-5f);
    float s2 = ge[oc]*inve;
    float4 r;
    float y;
    y = silu_f((acc[o][0] - m1[oc])*s1 + b1[oc]); r.x = fmaxf((y - me[oc])*s2 + be[oc], 0.f);
    y = silu_f((acc[o][1] - m1[oc])*s1 + b1[oc]); r.y = fmaxf((y - me[oc])*s2 + be[oc], 0.f);
    y = silu_f((acc[o][2] - m1[oc])*s1 + b1[oc]); r.z = fmaxf((y - me[oc])*s2 + be[oc], 0.f);
    y = silu_f((acc[o][3] - m1[oc])*s1 + b1[oc]); r.w = fmaxf((y - me[oc])*s2 + be[oc], 0.f);
    *(float4*)(x2 + ((long)img*128 + oc)*HW4 + prow) = r;
  }
}

// ---------------- conv2: 1x1 128->64 + BN + SiLU -> desc (into d_out) ------
// 4 oc x 4 px per thread; grid 256.
__global__ __launch_bounds__(256) void fm_conv2(
    const float* __restrict__ x2, const float* __restrict__ w,
    const float* __restrict__ g, const float* __restrict__ bb,
    const float* __restrict__ mm, const float* __restrict__ vv,
    float* __restrict__ out) {
  __shared__ float wl[128*4];
  int bid = blockIdx.x;
  int pblk = bid & 3, ocg = (bid >> 2) & 15, img = bid >> 6;
  int oc0 = ocg * 4;
  int tid = threadIdx.x;
  for (int i = tid; i < 512; i += 256) {
    int o = i & 3, ic = i >> 2;
    wl[i] = w[(oc0 + o)*128 + ic];
  }
  __syncthreads();
  int p0 = pblk*1024 + tid*4;
  const float* src = x2 + (long)img*128*HW4;
  float acc[4][4];
  #pragma unroll
  for (int o = 0; o < 4; ++o)
    #pragma unroll
    for (int j = 0; j < 4; ++j) acc[o][j] = 0.f;
  #pragma unroll 4
  for (int ic = 0; ic < 128; ++ic) {
    float4 v = *(const float4*)(src + (long)ic*HW4 + p0);
    float4 wa = *(const float4*)&wl[ic*4];
    acc[0][0] = fmaf(wa.x, v.x, acc[0][0]); acc[0][1] = fmaf(wa.x, v.y, acc[0][1]);
    acc[0][2] = fmaf(wa.x, v.z, acc[0][2]); acc[0][3] = fmaf(wa.x, v.w, acc[0][3]);
    acc[1][0] = fmaf(wa.y, v.x, acc[1][0]); acc[1][1] = fmaf(wa.y, v.y, acc[1][1]);
    acc[1][2] = fmaf(wa.y, v.z, acc[1][2]); acc[1][3] = fmaf(wa.y, v.w, acc[1][3]);
    acc[2][0] = fmaf(wa.z, v.x, acc[2][0]); acc[2][1] = fmaf(wa.z, v.y, acc[2][1]);
    acc[2][2] = fmaf(wa.z, v.z, acc[2][2]); acc[2][3] = fmaf(wa.z, v.w, acc[2][3]);
    acc[3][0] = fmaf(wa.w, v.x, acc[3][0]); acc[3][1] = fmaf(wa.w, v.y, acc[3][1]);
    acc[3][2] = fmaf(wa.w, v.z, acc[3][2]); acc[3][3] = fmaf(wa.w, v.w, acc[3][3]);
  }
  #pragma unroll
  for (int o = 0; o < 4; ++o) {
    int oc = oc0 + o;
    float inv = 1.f / sqrtf(vv[oc] + 1e-5f);
    float sc = g[oc]*inv;
    float* dst = out + 18 + (long)img*262144 + (long)oc*HW4 + p0;
    #pragma unroll
    for (int j = 0; j < 4; ++j)
      dst[j] = silu_f((acc[o][j] - mm[oc])*sc + bb[oc]);
  }
}

// ---------------- resp + inv-norm ----------------
__global__ __launch_bounds__(256) void fm_resp(
    const float* __restrict__ out, float* __restrict__ resp, float* __restrict__ invn) {
  int t = blockIdx.x*256 + threadIdx.x;
  if (t >= NIMG*HW4) return;
  int img = t >> 12, p = t & 4095;
  const float* d = out + 18 + (long)img*262144;
  float s = 0.f;
  #pragma unroll
  for (int c = 0; c < 64; ++c) { float x = d[c*HW4 + p]; s = fmaf(x, x, s); }
  float r = sqrtf(s);
  resp[t] = r;
  invn[t] = 1.f / fmaxf(r, 1e-12f);
}

// ---------------- top-512 via full bitonic sort (desc value, asc index) ----
__global__ __launch_bounds__(1024) void fm_sort(
    const float* __restrict__ resp, int* __restrict__ topidx) {
  __shared__ unsigned long long keys[4096];
  int img = blockIdx.x, tid = threadIdx.x;
  const float* r = resp + (long)img*HW4;
  for (int i = tid; i < 4096; i += 1024) {
    unsigned int vb = __float_as_uint(r[i]);
    keys[i] = ((unsigned long long)vb << 32) | (unsigned int)(4095 - i);
  }
  __syncthreads();
  for (int k = 2; k <= 4096; k <<= 1) {
    for (int j = k >> 1; j > 0; j >>= 1) {
      for (int t = tid; t < 2048; t += 1024) {
        int i = 2*t - (t & (j - 1));
        int ixj = i ^ j;
        bool up = ((i & k) == 0);
        unsigned long long a = keys[i], b = keys[ixj];
        if ((a < b) == up) { keys[i] = b; keys[ixj] = a; }
      }
      __syncthreads();
    }
  }
  if (tid < 512) topidx[img*512 + tid] = 4095 - (int)(keys[tid] & 0xFFFFFFFFull);
}

// ---------------- qgather ----------------
__global__ __launch_bounds__(256) void fm_qgather(
    const float* __restrict__ out, const float* __restrict__ invn,
    const int* __restrict__ topidx, float* __restrict__ qn) {
  int tid = threadIdx.x;
  int kp = blockIdx.x*4 + (tid >> 6);
  int c = tid & 63;
  int b = kp >> 9, k = kp & 511;
  int row = topidx[b*512 + k];
  const float* d1 = out + 18 + (long)b*262144;
  qn[(long)kp*64 + c] = d1[c*HW4 + row] * invn[(long)b*HW4 + row];
}

// ---------------- corr: tiled GEMM + online softmax partials ---------------
__global__ __launch_bounds__(256) void fm_corr(
    const float* __restrict__ out, const float* __restrict__ invn,
    const float* __restrict__ qn, float* __restrict__ part) {
  __shared__ float Qs[32*64];
  __shared__ float Ds[64*128];
  int tid = threadIdx.x;
  int tx = tid & 31, ty = tid >> 5;
  int jsplit = blockIdx.x;
  int kg = blockIdx.y;
  int b = blockIdx.z;
  int k0 = kg*32;
  const float* d2 = out + 18 + (long)(2 + b)*262144;
  const float* in2 = invn + (long)(2 + b)*HW4;
  {
    const float4* src = (const float4*)(qn + ((long)b*512 + k0)*64);
    float4* dst = (float4*)Qs;
    dst[tid] = src[tid];
    dst[tid + 256] = src[tid + 256];
  }
  float m[4], s[4];
  #pragma unroll
  for (int r = 0; r < 4; ++r) { m[r] = -INFINITY; s[r] = 0.f; }
  #pragma unroll
  for (int tile = 0; tile < 2; ++tile) {
    int j0 = jsplit*256 + tile*128;
    __syncthreads();
    {
      float4* dst = (float4*)Ds;
      #pragma unroll
      for (int t = 0; t < 8; ++t) {
        int i = tid + 256*t;
        int c = i >> 5, col4 = i & 31;
        dst[i] = *(const float4*)(d2 + (long)c*HW4 + j0 + col4*4);
      }
    }
    __syncthreads();
    float acc[4][4];
    #pragma unroll
    for (int r = 0; r < 4; ++r)
      #pragma unroll
      for (int cc = 0; cc < 4; ++cc) acc[r][cc] = 0.f;
    const float4* Ds4 = (const float4*)Ds;
    #pragma unroll 4
    for (int c = 0; c < 64; ++c) {
      float4 dv = Ds4[c*32 + tx];
      #pragma unroll
      for (int r = 0; r < 4; ++r) {
        float qv = Qs[(ty*4 + r)*64 + c];
        acc[r][0] = fmaf(qv, dv.x, acc[r][0]);
        acc[r][1] = fmaf(qv, dv.y, acc[r][1]);
        acc[r][2] = fmaf(qv, dv.z, acc[r][2]);
        acc[r][3] = fmaf(qv, dv.w, acc[r][3]);
      }
    }
    float i0 = in2[j0 + tx*4 + 0];
    float i1 = in2[j0 + tx*4 + 1];
    float i2 = in2[j0 + tx*4 + 2];
    float i3 = in2[j0 + tx*4 + 3];
    #pragma unroll
    for (int r = 0; r < 4; ++r) {
      float v0 = acc[r][0]*i0, v1 = acc[r][1]*i1, v2 = acc[r][2]*i2, v3 = acc[r][3]*i3;
      float vm = fmaxf(fmaxf(v0, v1), fmaxf(v2, v3));
      float nm = fmaxf(m[r], vm);
      s[r] = s[r]*expf(m[r] - nm) + expf(v0 - nm) + expf(v1 - nm) + expf(v2 - nm) + expf(v3 - nm);
      m[r] = nm;
    }
  }
  #pragma unroll
  for (int off = 1; off < 32; off <<= 1) {
    #pragma unroll
    for (int r = 0; r < 4; ++r) {
      float om = __shfl_xor(m[r], off);
      float os = __shfl_xor(s[r], off);
      float nm = fmaxf(m[r], om);
      s[r] = s[r]*expf(m[r] - nm) + os*expf(om - nm);
      m[r] = nm;
    }
  }
  if (tx == 0) {
    #pragma unroll
    for (int r = 0; r < 4; ++r) {
      long idx = (((long)b*512 + k0 + ty*4 + r)*NSPLIT + jsplit)*2;
      part[idx] = m[r];
      part[idx + 1] = s[r];
    }
  }
}

// ---------------- comb ----------------
__global__ __launch_bounds__(256) void fm_comb(
    const float* __restrict__ out, const float* __restrict__ invn,
    const int* __restrict__ topidx, const float* __restrict__ qn,
    const float* __restrict__ part, float* __restrict__ wts) {
  int tid = threadIdx.x;
  int kp = blockIdx.x*4 + (tid >> 6);
  int lane = tid & 63;
  int b = kp >> 9, k = kp & 511;
  int col = topidx[(2 + b)*512 + k];
  const float* d2 = out + 18 + (long)(2 + b)*262144;
  float dot = qn[(long)kp*64 + lane] * d2[lane*HW4 + col];
  #pragma unroll
  for (int off = 1; off < 64; off <<= 1) dot += __shfl_xor(dot, off);
  if (lane == 0) {
    const float* pp = part + (long)kp*NSPLIT*2;
    float M = -INFINITY;
    #pragma unroll
    for (int i = 0; i < NSPLIT; ++i) M = fmaxf(M, pp[2*i]);
    float S = 0.f;
    #pragma unroll
    for (int i = 0; i < NSPLIT; ++i) S += pp[2*i + 1]*expf(pp[2*i] - M);
    float v = dot * invn[(long)(2 + b)*HW4 + col];
    wts[b*512 + k] = expf(v - M)/S;
  }
}

// ---------------- build DLT rows ----------------
__global__ __launch_bounds__(256) void fm_build(
    const int* __restrict__ topidx, const float* __restrict__ wts,
    float* __restrict__ A) {
  int t = blockIdx.x*256 + threadIdx.x;
  if (t >= 1024) return;
  int b = t >> 9, k = t & 511;
  int i1 = topidx[b*512 + k], i2 = topidx[(2 + b)*512 + k];
  float w = wts[b*512 + k];
  float x1 = (float)(i1 & 63) / 63.f * 2.f - 1.f;
  float y1 = (float)(i1 >> 6) / 63.f * 2.f - 1.f;
  float x2 = (float)(i2 & 63) / 63.f * 2.f - 1.f;
  float y2 = (float)(i2 >> 6) / 63.f * 2.f - 1.f;
  float* r = A + ((long)b*1024 + 2*k)*9;
  r[0] = x1*w;  r[1] = y1*w;  r[2] = w;
  r[3] = 0.f;   r[4] = 0.f;   r[5] = 0.f;
  r[6] = (-x2*x1)*w; r[7] = (-x2*y1)*w; r[8] = (-x2)*w;
  r[9]  = 0.f;  r[10] = 0.f;  r[11] = 0.f;
  r[12] = x1*w; r[13] = y1*w; r[14] = w;
  r[15] = (-y2*x1)*w; r[16] = (-y2*y1)*w; r[17] = (-y2)*w;
}

// =========================== LAPACK ports ===================================
__device__ __forceinline__ void lap_slartg(float f, float g, float* cs, float* sn, float* r) {
  if (g == 0.f) { *cs = 1.f; *sn = 0.f; *r = f; }
  else if (f == 0.f) { *cs = 0.f; *sn = copysignf(1.f, g); *r = fabsf(g); }
  else {
    float d = sqrtf(f*f + g*g);
    *cs = fabsf(f) / d;
    *r = copysignf(d, f);
    *sn = g / (*r);
  }
}

__device__ __forceinline__ void lap_slas2(float f, float g, float h, float* ssmin, float* ssmax) {
  float fa = fabsf(f), ga = fabsf(g), ha = fabsf(h);
  float fhmn = fminf(fa, ha), fhmx = fmaxf(fa, ha);
  if (fhmn == 0.f) {
    *ssmin = 0.f;
    if (fhmx == 0.f) *ssmax = ga;
    else {
      float mx = fmaxf(fhmx, ga), mn = fminf(fhmx, ga);
      float q = mn / mx;
      *ssmax = mx * sqrtf(1.f + q*q);
    }
  } else {
    if (ga < fhmx) {
      float as_ = 1.f + fhmn/fhmx;
      float at_ = (fhmx - fhmn)/fhmx;
      float au = ga/fhmx; au = au*au;
      float c = 2.f / (sqrtf(as_*as_ + au) + sqrtf(at_*at_ + au));
      *ssmin = fhmn*c;
      *ssmax = fhmx/c;
    } else {
      float au = fhmx/ga;
      if (au == 0.f) { *ssmin = (fhmn*fhmx)/ga; *ssmax = ga; }
      else {
        float as_ = 1.f + fhmn/fhmx;
        float at_ = (fhmx - fhmn)/fhmx;
        float t1 = as_*au, t2 = at_*au;
        float c = 1.f / (sqrtf(1.f + t1*t1) + sqrtf(1.f + t2*t2));
        float smn = (fhmn*c)*au;
        *ssmin = smn + smn;
        *ssmax = ga/(c + c);
      }
    }
  }
}

__device__ __forceinline__ void lap_slasv2(float f, float g, float h, float* ssmin, float* ssmax,
                           float* snr, float* csr, float* snl, float* csl) {
  const float epsv = 5.9604645e-08f;
  float ft = f, fa = fabsf(f), ht = h, ha = fabsf(h);
  int pmax = 1;
  bool swap_ = (ha > fa);
  if (swap_) { pmax = 3; float tmp = ft; ft = ht; ht = tmp; tmp = fa; fa = ha; ha = tmp; }
  float gt = g, ga = fabsf(gt);
  float clt = 0.f, crt = 0.f, slt = 0.f, srt = 0.f;
  if (ga == 0.f) { *ssmin = ha; *ssmax = fa; clt = 1.f; crt = 1.f; slt = 0.f; srt = 0.f; }
  else {
    bool gasmal = true;
    if (ga > fa) {
      pmax = 2;
      if ((fa/ga) < epsv) {
        gasmal = false;
        *ssmax = ga;
        if (ha > 1.f) *ssmin = fa/(ga/ha); else *ssmin = (fa/ga)*ha;
        clt = 1.f; slt = ht/gt; srt = 1.f; crt = ft/gt;
      }
    }
    if (gasmal) {
      float d = fa - ha, l;
      if (d == fa) l = 1.f; else l = d/fa;
      float m_ = gt/ft;
      float t = 2.f - l;
      float mm2 = m_*m_, tt = t*t;
      float s = sqrtf(tt + mm2);
      float r_ = (l == 0.f) ? fabsf(m_) : sqrtf(l*l + mm2);
      float a = 0.5f*(s + r_);
      *ssmin = ha/a;
      *ssmax = fa*a;
      if (mm2 == 0.f) {
        if (l == 0.f) t = copysignf(2.f, ft)*copysignf(1.f, gt);
        else t = gt/copysignf(d, ft) + m_/t;
      } else {
        t = (m_/(s + t) + m_/(r_ + l))*(1.f + a);
      }
      float l2 = sqrtf(t*t + 4.f);
      crt = 2.f/l2;
      srt = t/l2;
      clt = (crt + srt*m_)/a;
      slt = (ht/ft)*srt/a;
    }
  }
  if (swap_) { *csl = srt; *snl = crt; *csr = slt; *snr = clt; }
  else { *csl = clt; *snl = slt; *csr = crt; *snr = srt; }
  float tsign = 1.f;
  if (pmax == 1) tsign = copysignf(1.f, *csr)*copysignf(1.f, *csl)*copysignf(1.f, f);
  if (pmax == 2) tsign = copysignf(1.f, *snr)*copysignf(1.f, *csl)*copysignf(1.f, g);
  if (pmax == 3) tsign = copysignf(1.f, *snr)*copysignf(1.f, *snl)*copysignf(1.f, h);
  *ssmax = copysignf(*ssmax, tsign);
  *ssmin = copysignf(*ssmin, tsign*copysignf(1.f, f)*copysignf(1.f, h));
}

// runtime-uniform-index register array helpers
__device__ __forceinline__ float get9(const float (&a)[9], int idx) {
  float v = a[0];
#pragma unroll
  for (int i = 1; i < 9; ++i) if (idx == i) v = a[i];
  return v;
}
__device__ __forceinline__ void set9(float (&a)[9], int idx, float val) {
#pragma unroll
  for (int i = 0; i < 9; ++i) if (idx == i) a[i] = val;
}

// register-resident sbdsqr, n=9 (see R5 notes)
__device__ __forceinline__ void bdsqr9_reg(float (&dd)[9], float (&ee)[9], float (&vt)[9]) {
  const float eps_ = 5.9604645e-08f;
  const float unfl_ = 1.17549435e-38f;
  const float tol_ = 10.f*eps_;
  float sminoa = fabsf(dd[0]);
  if (sminoa != 0.f) {
    float mu = sminoa;
    bool z = false;
#pragma unroll
    for (int i = 1; i < 9; ++i) {
      if (!z) {
        mu = fabsf(dd[i])*(mu/(mu + fabsf(ee[i-1])));
        sminoa = fminf(sminoa, mu);
        if (sminoa == 0.f) z = true;
      }
    }
  }
  sminoa = sminoa / 3.f;
  float thresh = fmaxf(tol_*sminoa, 486.f*unfl_);
  int m = 9, iter = 0, oldll = -1, oldm = -1, idir = 0;
  float sminl = 0.f;
  int guard = 0;
  while (guard++ < 2000) {
    if (m <= 1) break;
    if (iter > 486) break;
    float smax = fabsf(get9(dd, m-1));
    int ll = 0; bool split = false;
#pragma unroll
    for (int l2 = 8; l2 >= 1; --l2) {
      if (l2 <= m - 1 && !split) {
        float abss = fabsf(dd[l2-1]);
        float abse = fabsf(ee[l2-1]);
        if (abse <= thresh) { ll = l2; split = true; }
        else smax = fmaxf(smax, fmaxf(abss, abse));
      }
    }
    if (split) {
      set9(ee, ll-1, 0.f);
      if (ll == m - 1) { m = m - 1; continue; }
    } else ll = 0;
    ll = ll + 1;
    if (ll == m - 1) {
      float d1 = get9(dd, m-2), e1 = get9(ee, m-2), d2v = get9(dd, m-1);
      float sigmn, sigmx, sinr, cosr, sinl_, cosl_;
      lap_slasv2(d1, e1, d2v, &sigmn, &sigmx, &sinr, &cosr, &sinl_, &cosl_);
      set9(dd, m-2, sigmx); set9(ee, m-2, 0.f); set9(dd, m-1, sigmn);
      float xt = get9(vt, m-2), yt = get9(vt, m-1);
      set9(vt, m-2, cosr*xt + sinr*yt);
      set9(vt, m-1, cosr*yt - sinr*xt);
      m -= 2; continue;
    }
    if (ll > oldm || m < oldll)
      idir = (fabsf(get9(dd, ll-1)) >= fabsf(get9(dd, m-1))) ? 1 : 2;
    bool conv = false;
    if (idir == 1) {
      if (fabsf(get9(ee, m-2)) <= tol_*fabsf(get9(dd, m-1))) { set9(ee, m-2, 0.f); continue; }
      float mu = fabsf(get9(dd, ll-1));
      sminl = mu;
#pragma unroll
      for (int lll = 1; lll <= 8; ++lll) {
        if (lll >= ll && lll <= m - 1 && !conv) {
          if (fabsf(ee[lll-1]) <= tol_*mu) { ee[lll-1] = 0.f; conv = true; }
          else {
            mu = fabsf(dd[lll])*(mu/(mu + fabsf(ee[lll-1])));
            sminl = fminf(sminl, mu);
          }
        }
      }
    } else {
      if (fabsf(get9(ee, ll-1)) <= tol_*fabsf(get9(dd, ll-1))) { set9(ee, ll-1, 0.f); continue; }
      float mu = fabsf(get9(dd, m-1));
      sminl = mu;
#pragma unroll
      for (int lll = 8; lll >= 1; --lll) {
        if (lll <= m - 1 && lll >= ll && !conv) {
          if (fabsf(ee[lll-1]) <= tol_*mu) { ee[lll-1] = 0.f; conv = true; }
          else {
            mu = fabsf(dd[lll-1])*(mu/(mu + fabsf(ee[lll-1])));
            sminl = fminf(sminl, mu);
          }
        }
      }
    }
    if (conv) continue;
    oldll = ll; oldm = m;
    float shift = 0.f, rdum;
    if (!(9.f*tol_*(sminl/smax) <= fmaxf(eps_, 0.01f*tol_))) {
      float sll;
      if (idir == 1) { sll = fabsf(get9(dd, ll-1)); lap_slas2(get9(dd, m-2), get9(ee, m-2), get9(dd, m-1), &shift, &rdum); }
      else           { sll = fabsf(get9(dd, m-1));  lap_slas2(get9(dd, ll-1), get9(ee, ll-1), get9(dd, ll), &shift, &rdum); }
      if (sll > 0.f) { float q = shift/sll; if (q*q < eps_) shift = 0.f; }
    }
    iter += m - ll;
    if (shift == 0.f) {
      if (idir == 1) {
        float cs = 1.f, oldcs = 1.f, sn = 0.f, oldsn = 0.f, r;
#pragma unroll
        for (int i = 1; i <= 8; ++i) {
          if (i >= ll && i <= m - 1) {
            lap_slartg(dd[i-1]*cs, ee[i-1], &cs, &sn, &r);
            if (i >= 2 && i > ll) ee[i-2] = oldsn*r;
            float dn;
            lap_slartg(oldcs*r, dd[i]*sn, &oldcs, &oldsn, &dn);
            dd[i-1] = dn;
            float t = vt[i]; vt[i] = cs*t - sn*vt[i-1]; vt[i-1] = sn*t + cs*vt[i-1];
          }
        }
        float h2 = get9(dd, m-1)*cs;
        set9(dd, m-1, h2*oldcs);
        set9(ee, m-2, h2*oldsn);
        if (fabsf(get9(ee, m-2)) <= thresh) set9(ee, m-2, 0.f);
      } else {
        float cs = 1.f, oldcs = 1.f, sn = 0.f, oldsn = 0.f, r;
#pragma unroll
        for (int i = 9; i >= 2; --i) {
          if (i <= m && i >= ll + 1) {
            lap_slartg(dd[i-1]*cs, ee[i-2], &cs, &sn, &r);
            if (i < m) ee[i-1] = oldsn*r;
            float dn;
            lap_slartg(oldcs*r, dd[i-2]*sn, &oldcs, &oldsn, &dn);
            dd[i-1] = dn;
            float c2 = oldcs, s2 = -oldsn;
            float t = vt[i-1]; vt[i-1] = c2*t - s2*vt[i-2]; vt[i-2] = s2*t + c2*vt[i-2];
          }
        }
        float h2 = get9(dd, ll-1)*cs;
        set9(dd, ll-1, h2*oldcs);
        set9(ee, ll-1, h2*oldsn);
        if (fabsf(get9(ee, ll-1)) <= thresh) set9(ee, ll-1, 0.f);
      }
    } else {
      if (idir == 1) {
        float d0 = get9(dd, ll-1);
        float f2 = (fabsf(d0) - shift)*(copysignf(1.f, d0) + shift/d0);
        float g2 = get9(ee, ll-1);
#pragma unroll
        for (int i = 1; i <= 8; ++i) {
          if (i >= ll && i <= m - 1) {
            float cr, sr, cl, sl, r;
            lap_slartg(f2, g2, &cr, &sr, &r);
            if (i >= 2 && i > ll) ee[i-2] = r;
            f2 = cr*dd[i-1] + sr*ee[i-1];
            ee[i-1] = cr*ee[i-1] - sr*dd[i-1];
            g2 = sr*dd[i];
            dd[i] = cr*dd[i];
            lap_slartg(f2, g2, &cl, &sl, &r);
            dd[i-1] = r;
            f2 = cl*ee[i-1] + sl*dd[i];
            dd[i] = cl*dd[i] - sl*ee[i-1];
            if (i < m - 1) { g2 = sl*ee[i]; ee[i] = cl*ee[i]; }
            float t = vt[i]; vt[i] = cr*t - sr*vt[i-1]; vt[i-1] = sr*t + cr*vt[i-1];
          }
        }
        set9(ee, m-2, f2);
        if (fabsf(get9(ee, m-2)) <= thresh) set9(ee, m-2, 0.f);
      } else {
        float dm = get9(dd, m-1);
        float f2 = (fabsf(dm) - shift)*(copysignf(1.f, dm) + shift/dm);
        float g2 = get9(ee, m-2);
#pragma unroll
        for (int i = 9; i >= 2; --i) {
          if (i <= m && i >= ll + 1) {
            float cr, sr, cl, sl, r;
            lap_slartg(f2, g2, &cr, &sr, &r);
            if (i < m) ee[i-1] = r;
            f2 = cr*dd[i-1] + sr*ee[i-2];
            ee[i-2] = cr*ee[i-2] - sr*dd[i-1];
            g2 = sr*dd[i-2];
            dd[i-2] = cr*dd[i-2];
            lap_slartg(f2, g2, &cl, &sl, &r);
            dd[i-1] = r;
            f2 = cl*ee[i-2] + sl*dd[i-2];
            dd[i-2] = cl*dd[i-2] - sl*ee[i-2];
            if (i >= 3 && i > ll + 1) { g2 = sl*ee[i-3]; ee[i-3] = cl*ee[i-3]; }
            float c2 = cl, s2 = -sl;
            float t = vt[i-1]; vt[i-1] = c2*t - s2*vt[i-2]; vt[i-2] = s2*t + c2*vt[i-2];
          }
        }
        set9(ee, ll-1, f2);
        if (fabsf(get9(ee, ll-1)) <= thresh) set9(ee, ll-1, 0.f);
      }
    }
  }
#pragma unroll
  for (int i = 0; i < 9; ++i) {
    if (dd[i] < 0.f) { dd[i] = -dd[i]; vt[i] = -vt[i]; }
  }
#pragma unroll
  for (int i = 1; i <= 8; ++i) {
    int isub = 1; float smin2 = dd[0];
#pragma unroll
    for (int j = 2; j <= 9; ++j) {
      if (j <= 10 - i) {
        if (dd[j-1] <= smin2) { isub = j; smin2 = dd[j-1]; }
      }
    }
    const int tgt = 10 - i;
    if (isub != tgt) {
      set9(dd, isub-1, dd[tgt-1]);
      dd[tgt-1] = smin2;
      float tv = get9(vt, isub-1);
      set9(vt, isub-1, vt[tgt-1]);
      vt[tgt-1] = tv;
    }
  }
}

// ---------------- SVD kernel: batched-larf QR + register gebrd/bdsqr -------
__global__ __launch_bounds__(256) void fm_svd(
    const float* __restrict__ Aglob, float* __restrict__ outH) {
  __shared__ float As[1024*9];
  __shared__ float wred[4][12];
  __shared__ float bc[4];
  int b = blockIdx.x, tid = threadIdx.x;
  int wv = tid >> 6, ln = tid & 63;
  const float* Ab = Aglob + (long)b*9216;
  {
    const float4* s4 = (const float4*)Ab;
    float4* d4 = (float4*)As;
#pragma unroll
    for (int t = 0; t < 9; ++t) d4[tid + 256*t] = s4[tid + 256*t];
  }
  __syncthreads();
  for (int k = 0; k < 9; ++k) {
    float ps = 0.f;
    for (int r = k + 1 + tid; r < 1024; r += 256) {
      float x = As[r*9 + k]; ps = fmaf(x, x, ps);
    }
#pragma unroll
    for (int off = 1; off < 64; off <<= 1) ps += __shfl_xor(ps, off);
    if (ln == 0) wred[wv][8] = ps;
    __syncthreads();
    if (tid == 0) {
      float ssq = wred[0][8] + wred[1][8] + wred[2][8] + wred[3][8];
      float alpha = As[k*9 + k];
      float tau = 0.f, sc = 0.f, beta = alpha;
      if (ssq != 0.f) {
        beta = -copysignf(sqrtf(alpha*alpha + ssq), alpha);
        tau = (beta - alpha)/beta;
        sc = 1.f/(alpha - beta);
      }
      bc[0] = tau; bc[1] = sc; bc[2] = beta;
    }
    __syncthreads();
    float tau = bc[0], sc = bc[1];
    if (tau != 0.f) {
      for (int r = k + 1 + tid; r < 1024; r += 256) As[r*9 + k] *= sc;
    }
    __syncthreads();
    if (tau != 0.f) {
      float pd[8];
#pragma unroll
      for (int jj = 0; jj < 8; ++jj) pd[jj] = 0.f;
      for (int r = k + 1 + tid; r < 1024; r += 256) {
        float vk = As[r*9 + k];
#pragma unroll
        for (int jj = 0; jj < 8; ++jj) {
          int j = k + 1 + jj;
          if (j < 9) pd[jj] = fmaf(vk, As[r*9 + j], pd[jj]);
        }
      }
#pragma unroll
      for (int off = 1; off < 64; off <<= 1) {
#pragma unroll
        for (int jj = 0; jj < 8; ++jj) pd[jj] += __shfl_xor(pd[jj], off);
      }
      if (ln == 0) {
#pragma unroll
        for (int jj = 0; jj < 8; ++jj) wred[wv][jj] = pd[jj];
      }
      __syncthreads();
      float sj[8];
#pragma unroll
      for (int jj = 0; jj < 8; ++jj) {
        int j = k + 1 + jj;
        float v = 0.f;
        if (j < 9)
          v = (wred[0][jj] + wred[1][jj] + wred[2][jj] + wred[3][jj] + As[k*9 + j]) * tau;
        sj[jj] = v;
      }
      for (int r = k + 1 + tid; r < 1024; r += 256) {
        float vk = As[r*9 + k];
#pragma unroll
        for (int jj = 0; jj < 8; ++jj) {
          int j = k + 1 + jj;
          if (j < 9) As[r*9 + j] -= sj[jj]*vk;
        }
      }
      __syncthreads();
      if (tid == 0) {
#pragma unroll
        for (int jj = 0; jj < 8; ++jj) {
          int j = k + 1 + jj;
          if (j < 9) As[k*9 + j] -= sj[jj];
        }
      }
    }
    if (tid == 0) As[k*9 + k] = bc[2];
    __syncthreads();
  }
  if (tid < 64) {
    float R[9][9];
#pragma unroll
    for (int i = 0; i < 9; ++i)
#pragma unroll
      for (int j = 0; j < 9; ++j)
        R[i][j] = (j >= i) ? As[i*9 + j] : 0.f;
    float dd[9], ee[9], taupv[8], pt8[9];
    ee[8] = 0.f;
#pragma unroll
    for (int i = 0; i < 9; ++i) {
      float alpha = R[i][i];
      float ssq = 0.f;
#pragma unroll
      for (int r2 = i + 1; r2 < 9; ++r2) ssq += R[r2][i]*R[r2][i];
      float tauq = 0.f, beta = alpha;
      if (ssq != 0.f) {
        beta = -copysignf(sqrtf(alpha*alpha + ssq), alpha);
        tauq = (beta - alpha)/beta;
        float scq = 1.f/(alpha - beta);
#pragma unroll
        for (int r2 = i + 1; r2 < 9; ++r2) R[r2][i] *= scq;
      }
      dd[i] = beta;
      if (tauq != 0.f) {
#pragma unroll
        for (int j = i + 1; j < 9; ++j) {
          float s = R[i][j];
#pragma unroll
          for (int r2 = i + 1; r2 < 9; ++r2) s += R[r2][i]*R[r2][j];
          s *= tauq;
          R[i][j] -= s;
#pragma unroll
          for (int r2 = i + 1; r2 < 9; ++r2) R[r2][j] -= s*R[r2][i];
        }
      }
      if (i < 8) {
        float alpha2 = R[i][i+1];
        float ssq2 = 0.f;
#pragma unroll
        for (int c = i + 2; c < 9; ++c) ssq2 += R[i][c]*R[i][c];
        float tp = 0.f, beta2 = alpha2;
        if (ssq2 != 0.f) {
          beta2 = -copysignf(sqrtf(alpha2*alpha2 + ssq2), alpha2);
          tp = (beta2 - alpha2)/beta2;
          float scp = 1.f/(alpha2 - beta2);
#pragma unroll
          for (int c = i + 2; c < 9; ++c) R[i][c] *= scp;
        }
        ee[i] = beta2;
        taupv[i] = tp;
        if (tp != 0.f) {
#pragma unroll
          for (int r2 = i + 1; r2 < 9; ++r2) {
            float s = R[r2][i+1];
#pragma unroll
            for (int c = i + 2; c < 9; ++c) s += R[i][c]*R[r2][c];
            s *= tp;
            R[r2][i+1] -= s;
#pragma unroll
            for (int c = i + 2; c < 9; ++c) R[r2][c] -= s*R[i][c];
          }
        }
      }
    }
#pragma unroll
    for (int i = 0; i < 9; ++i) pt8[i] = (i == 8) ? 1.f : 0.f;
#pragma unroll
    for (int i = 0; i < 8; ++i) {
      float tp = taupv[i];
      if (tp != 0.f) {
        float s = pt8[i+1];
#pragma unroll
        for (int r2 = i + 2; r2 < 9; ++r2) s += R[i][r2]*pt8[r2];
        s *= tp;
        pt8[i+1] -= s;
#pragma unroll
        for (int r2 = i + 2; r2 < 9; ++r2) pt8[r2] -= s*R[i][r2];
      }
    }
    float vt[9];
#pragma unroll
    for (int i = 0; i < 9; ++i) vt[i] = (i == tid) ? 1.f : 0.f;
    bdsqr9_reg(dd, ee, vt);
    float p8 = (tid < 9) ? get9(pt8, tid) : 0.f;
    float h[9];
#pragma unroll
    for (int i = 0; i < 9; ++i) h[i] = vt[i]*p8;
#pragma unroll
    for (int off = 1; off < 16; off <<= 1) {
#pragma unroll
      for (int i = 0; i < 9; ++i) h[i] += __shfl_xor(h[i], off);
    }
    if (tid == 0) {
#pragma unroll
      for (int i = 0; i < 9; ++i) outH[b*9 + i] = h[i];
    }
  }
}

// ===========================================================================
extern "C" void kernel_launch(void* const* d_in, const int* in_sizes, int n_in,
                              void* d_out, int out_size, void* d_ws, size_t ws_size,
                              hipStream_t stream) {
  const float* rgb  = (const float*)d_in[0];
  const float* ir   = (const float*)d_in[1];
  const float* w_dr = (const float*)d_in[2];
  const float* g_dr = (const float*)d_in[3];
  const float* b_dr = (const float*)d_in[4];
  const float* m_dr = (const float*)d_in[5];
  const float* v_dr = (const float*)d_in[6];
  const float* w_d1 = (const float*)d_in[7];
  const float* g_d1 = (const float*)d_in[8];
  const float* b_d1 = (const float*)d_in[9];
  const float* m_d1 = (const float*)d_in[10];
  const float* v_d1 = (const float*)d_in[11];
  const float* g_e  = (const float*)d_in[12];
  const float* b_e  = (const float*)d_in[13];
  const float* m_e  = (const float*)d_in[14];
  const float* v_e  = (const float*)d_in[15];
  const float* w_d2 = (const float*)d_in[16];
  const float* g_d2 = (const float*)d_in[17];
  const float* b_d2 = (const float*)d_in[18];
  const float* m_d2 = (const float*)d_in[19];
  const float* v_d2 = (const float*)d_in[20];

  float* out = (float*)d_out;
  float* ws  = (float*)d_ws;
  float* x1   = ws + OFF_X1;
  float* x2   = ws + OFF_X2;
  float* resp = ws + OFF_RESP;
  float* invn = ws + OFF_INVN;
  int*   topi = (int*)(ws + OFF_TOPI);
  float* wts  = ws + OFF_WTS;
  float* Amat = ws + OFF_A;
  float* qn   = ws + OFF_QN;     // aliases x1 (free after conv3)
  float* part = ws + OFF_PART;   // aliases x1

  fm_conv1<<<256, 256, 0, stream>>>(rgb, ir, w_dr, g_dr, b_dr, m_dr, v_dr, x1);
  fm_conv3<<<256, 256, 0, stream>>>(x1, w_d1, g_d1, b_d1, m_d1, v_d1,
                                    g_e, b_e, m_e, v_e, x2);
  fm_conv2<<<256, 256, 0, stream>>>(x2, w_d2, g_d2, b_d2, m_d2, v_d2, out);
  fm_resp<<<(NIMG*HW4 + 255)/256, 256, 0, stream>>>(out, resp, invn);
  fm_sort<<<NIMG, 1024, 0, stream>>>(resp, topi);
  fm_qgather<<<256, 256, 0, stream>>>(out, invn, topi, qn);
  fm_corr<<<dim3(NSPLIT, 16, 2), 256, 0, stream>>>(out, invn, qn, part);
  fm_comb<<<256, 256, 0, stream>>>(out, invn, topi, qn, part, wts);
  fm_build<<<4, 256, 0, stream>>>(topi, wts, Amat);
  fm_svd<<<2, 256, 0, stream>>>(Amat, out);
}